// Round 8
// baseline (925.931 us; speedup 1.0000x reference)
//
#include <hip/hip_runtime.h>
#include <math.h>
#include <stddef.h>

#define WG 256

typedef short short8_t __attribute__((ext_vector_type(8)));
typedef float f32x4_t __attribute__((ext_vector_type(4)));

// ---------------------------------------------------------------------------
// Edge stats: in-degree (incl self) + self-edge count.
__global__ void edgestats_k(const int* __restrict__ esrc, const int* __restrict__ edst,
                            int* __restrict__ cnt, int* __restrict__ selfc, int E) {
  int e = blockIdx.x * blockDim.x + threadIdx.x;
  if (e >= E) return;
  int s = esrc[e], d = edst[e];
  atomicAdd(&cnt[d], 1);
  if (s == d) atomicAdd(&selfc[d], 1);
}

// Exclusive scan of cnt (4096) + fused level-0 degree finalize.
__global__ void __launch_bounds__(1024) exscanfin_k(const int* __restrict__ cnt,
                                                    const int* __restrict__ selfc,
                                                    int* __restrict__ off,
                                                    float* __restrict__ dinv,
                                                    float* __restrict__ fixv) {
  __shared__ int part[1024];
  int t = threadIdx.x;
  int l[4];
  l[0] = cnt[t * 4]; l[1] = cnt[t * 4 + 1]; l[2] = cnt[t * 4 + 2]; l[3] = cnt[t * 4 + 3];
  int s = l[0] + l[1] + l[2] + l[3];
  part[t] = s;
  __syncthreads();
  for (int d = 1; d < 1024; d <<= 1) {
    int v = part[t];
    int u = (t >= d) ? part[t - d] : 0;
    __syncthreads();
    part[t] = v + u;
    __syncthreads();
  }
  int ex = (t > 0) ? part[t - 1] : 0;
  off[t * 4] = ex;
  off[t * 4 + 1] = ex + l[0];
  off[t * 4 + 2] = ex + l[0] + l[1];
  off[t * 4 + 3] = ex + l[0] + l[1] + l[2];
  if (t == 1023) off[4096] = part[1023];
#pragma unroll
  for (int u = 0; u < 4; u++) {
    int i = t * 4 + u;
    float fx = (selfc[i] == 0) ? 2.0f : 0.0f;
    float deg = (float)l[u] + fx;
    dinv[i] = (deg > 0.f) ? 1.0f / sqrtf(deg) : 0.f;
    fixv[i] = fx;
  }
}

// in-CSR (by dst, incl self)
__global__ void scatterd_k(const int* __restrict__ esrc, const int* __restrict__ edst,
                           const int* __restrict__ off, int* __restrict__ fill,
                           int* __restrict__ bys, int E) {
  int e = blockIdx.x * blockDim.x + threadIdx.x;
  if (e >= E) return;
  int d = edst[e];
  int p = off[d] + atomicAdd(&fill[d], 1);
  bys[p] = esrc[e];
}

// SpMV: Z[d][c] = dinv[d]*(sum y[src][c] + fixv[d]*y[d][c]) + bias[c]
// SMAX: fuse row softmax (N<=64) writing probabilities.
template<int SMALL, int SMAX>
__global__ void __launch_bounds__(256) spmv_k(const int* __restrict__ off, const int* __restrict__ bys,
                                              const float* __restrict__ y, int N,
                                              const float* __restrict__ dinv, const float* __restrict__ fixv,
                                              const float* __restrict__ bias, int relu,
                                              float* __restrict__ Z) {
  int w = threadIdx.x >> 6, l = threadIdx.x & 63;
  int row = blockIdx.x * 4 + w;
  int b0 = off[row], b1 = off[row + 1];
  if (SMALL) {  // N == 32
    int c = l & 31, eh = l >> 5;
    float acc = 0.f;
    for (int e = b0 + eh; e < b1; e += 2) { int s = bys[e]; acc += y[(size_t)s * N + c]; }
    acc += __shfl_xor(acc, 32, 64);
    if (eh == 0) {
      float v = acc + fixv[row] * y[(size_t)row * N + c];
      v = v * dinv[row] + (bias ? bias[c] : 0.f);
      if (relu) v = fmaxf(v, 0.f);
      Z[(size_t)row * N + c] = v;
    }
  } else {
    bool act = l < N;
    float acc = 0.f;
    for (int e = b0; e < b1; e++) { int s = bys[e]; if (act) acc += y[(size_t)s * N + l]; }
    float v = 0.f;
    if (act) {
      v = acc + fixv[row] * y[(size_t)row * N + l];
      v = v * dinv[row] + (bias ? bias[l] : 0.f);
      if (relu) v = fmaxf(v, 0.f);
    }
    if (SMAX) {
      float mv = act ? v : -3.0e38f;
#pragma unroll
      for (int m = 1; m < 64; m <<= 1) mv = fmaxf(mv, __shfl_xor(mv, m, 64));
      float e = act ? expf(v - mv) : 0.f;
      float se = e;
#pragma unroll
      for (int m = 1; m < 64; m <<= 1) se += __shfl_xor(se, m, 64);
      if (act) Z[(size_t)row * N + l] = e / se;
    } else if (act) {
      Z[(size_t)row * N + l] = v;
    }
  }
}

// ---------------------------------------------------------------------------
// aug1, row-centric LDS SpGEMM (exact ints), fused rowsum -> dinv/fixv.
__global__ void __launch_bounds__(256) aug1row_k(
    const int* __restrict__ off, const int* __restrict__ bys,
    const int* __restrict__ perm, const int* __restrict__ rank1,
    float* __restrict__ A1, int m,
    float* __restrict__ dinv, float* __restrict__ fixv) {
  __shared__ float row[2048];
  __shared__ float red[WG];
  int tid = threadIdx.x;
  int rd = blockIdx.x;
  int d = perm[rd];
  for (int i = tid; i < m; i += WG) row[i] = 0.f;
  __syncthreads();
  int b0 = off[d], b1 = off[d + 1];
  int wave = tid >> 6, lane = tid & 63;
  for (int e = b0 + wave; e < b1; e += 4) {
    int k = bys[e];
    if (k == d) continue;
    int o0 = off[k], o1 = off[k + 1];
    for (int t = o0 + lane; t < o1; t += 64) {
      int j = bys[t];
      if (j == k) continue;
      int rj = rank1[j];
      if (rj >= 0) atomicAdd(&row[rj], 1.0f);
    }
  }
  for (int e = b0 + tid; e < b1; e += WG) {
    int j = bys[e];
    if (j == d) continue;
    int rj = rank1[j];
    if (rj >= 0) atomicAdd(&row[rj], 2.0f);
  }
  __syncthreads();
  if (tid == 0) row[rd] = 0.f;
  __syncthreads();
  float s = 0.f;
  float* Ar = A1 + (size_t)rd * m;
  for (int i = tid; i < m; i += WG) { float v = row[i]; s += v; Ar[i] = v; }
  red[tid] = s;
  __syncthreads();
  for (int dd = WG / 2; dd > 0; dd >>= 1) {
    if (tid < dd) red[tid] += red[tid + dd];
    __syncthreads();
  }
  if (tid == 0) {
    dinv[rd] = 1.0f / sqrtf(red[0] + 2.0f);
    fixv[rd] = 2.0f;
  }
}

// ---------------------------------------------------------------------------
// fp32 SGEMM. Fused mode (P==null): row scale/bias/relu, optional transposed
// store. Split-K mode (P!=null): blockIdx.z picks a Kc-chunk, raw partials.
// permL/permR (optional): L row a = S[permL[a]] + I; R col b = S[:,permR[b]] + I
// (square S, row length K).
template<int TNv>
__global__ void __launch_bounds__(256) sgemm_k(
    const float* __restrict__ L, const float* __restrict__ R, float* __restrict__ C,
    int M, int N, int K,
    const float* __restrict__ dinv, const float* __restrict__ bias, int relu,
    int transC, int ldc, float* __restrict__ P, int Kc,
    const int* __restrict__ permL, const int* __restrict__ permR) {
  const int MN = TNv / 16;
  __shared__ float Ls[16][68];
  __shared__ float Rs[16][TNv];
  int tid = threadIdx.x;
  int tx = tid & 15, ty = tid >> 4;
  int m0 = blockIdx.y * 64;
  int n0 = blockIdx.x * TNv;
  int kbeg = 0, kend = K;
  if (P) { kbeg = blockIdx.z * Kc; kend = kbeg + Kc; }
  float acc[4][MN];
#pragma unroll
  for (int i = 0; i < 4; i++)
#pragma unroll
    for (int j = 0; j < MN; j++) acc[i][j] = 0.f;

  int lk = tid & 15, lm = tid >> 4;
  int rn = tid % TNv, rk = tid / TNv;
  const int KSL = 256 / TNv;

  for (int kt = kbeg; kt < kend; kt += 16) {
#pragma unroll
    for (int r = 0; r < 4; r++) {
      int m = lm + r * 16;
      if (permL) {
        int pr = permL[m0 + m];
        float v = L[(size_t)pr * K + kt + lk];
        if (kt + lk == pr) v += 1.0f;
        Ls[lk][m] = v;
      } else {
        Ls[lk][m] = L[(size_t)(m0 + m) * K + kt + lk];
      }
    }
#pragma unroll
    for (int r = 0; r < 16 / KSL; r++) {
      int k = rk + r * KSL;
      int gn = n0 + rn;
      float v = 0.f;
      if (gn < N) {
        if (permR) {
          int pr = permR[gn];
          v = R[(size_t)(kt + k) * K + pr];
          if (kt + k == pr) v += 1.0f;
        } else {
          v = R[(size_t)(kt + k) * N + gn];
        }
      }
      Rs[k][rn] = v;
    }
    __syncthreads();
#pragma unroll
    for (int k = 0; k < 16; k++) {
      float a[4], b[MN];
#pragma unroll
      for (int i = 0; i < 4; i++) a[i] = Ls[k][ty * 4 + i];
#pragma unroll
      for (int j = 0; j < MN; j++) b[j] = Rs[k][tx * MN + j];
#pragma unroll
      for (int i = 0; i < 4; i++)
#pragma unroll
        for (int j = 0; j < MN; j++) acc[i][j] += a[i] * b[j];
    }
    __syncthreads();
  }
  if (P) {
    float* Pz = P + (size_t)blockIdx.z * M * N;
#pragma unroll
    for (int i = 0; i < 4; i++) {
      int gi = m0 + ty * 4 + i;
#pragma unroll
      for (int j = 0; j < MN; j++) {
        int gj = n0 + tx * MN + j;
        if (gj < N) Pz[(size_t)gi * N + gj] = acc[i][j];
      }
    }
    return;
  }
#pragma unroll
  for (int i = 0; i < 4; i++) {
    int gi = m0 + ty * 4 + i;
#pragma unroll
    for (int j = 0; j < MN; j++) {
      int gj = n0 + tx * MN + j;
      if (gj < N) {
        float v = acc[i][j];
        if (dinv) v *= dinv[gi];
        if (bias) v += bias[gj];
        if (relu) v = fmaxf(v, 0.f);
        if (transC) C[(size_t)gj * ldc + gi] = v;
        else C[(size_t)gi * N + gj] = v;
      }
    }
  }
}

// Elementwise split-K reduce + epilogue (non-square outputs).
__global__ void sgemmred_k(const float* __restrict__ P, float* __restrict__ C,
                           int M, int N, int KS,
                           const float* __restrict__ dinv, const float* __restrict__ bias,
                           int relu, int transC, int ldc) {
  int t = blockIdx.x * blockDim.x + threadIdx.x;
  if (t >= M * N) return;
  int i = t / N, j = t - i * N;
  float s = 0.f;
  for (int z = 0; z < KS; z++) s += P[(size_t)z * M * N + t];
  if (dinv) s *= dinv[i];
  if (bias) s += bias[j];
  if (relu) s = fmaxf(s, 0.f);
  if (transC) C[(size_t)j * ldc + i] = s;
  else C[t] = s;
}

// Row-oriented split-K reduce + zero diag + fused rowsum -> dinv/fixv (square).
__global__ void __launch_bounds__(256) mfredrow_k(const float* __restrict__ P, float* __restrict__ C,
                                                  int n, int KS,
                                                  float* __restrict__ dinv, float* __restrict__ fixv) {
  __shared__ float red[WG];
  int row = blockIdx.x, tid = threadIdx.x;
  float s = 0.f;
  for (int c = tid; c < n; c += WG) {
    float v = 0.f;
    size_t idx = (size_t)row * n + c;
    for (int z = 0; z < KS; z++) v += P[(size_t)z * n * n + idx];
    if (c == row) v = 0.f;
    C[idx] = v;
    s += v;
  }
  red[tid] = s;
  __syncthreads();
  for (int d = WG / 2; d > 0; d >>= 1) {
    if (tid < d) red[tid] += red[tid + d];
    __syncthreads();
  }
  if (tid == 0) {
    dinv[row] = 1.0f / sqrtf(red[0] + 2.0f);
    fixv[row] = 2.0f;
  }
}

// ---------------------------------------------------------------------------
// bf16 MFMA NT GEMM with perm indirection + on-the-fly +I, split-K:
// P[z] = (S+I)[perm] ( rows m0.. ) @ ((ST+I)[perm])^T over k-chunk z.
// Operand values exact small ints -> bf16 truncation exact.
__global__ void __launch_bounds__(256) mfma_ntp_k(const float* __restrict__ S,
                                                  const float* __restrict__ ST,
                                                  const int* __restrict__ perm,
                                                  float* __restrict__ P, int m, int lda, int Kc) {
  __shared__ short As[128 * 32];
  __shared__ short Bs[128 * 32];
  int tid = threadIdx.x;
  int w = tid >> 6, l = tid & 63;
  int wy = w >> 1, wx = w & 1;
  int q = l >> 4, r = l & 15;
  int m0 = blockIdx.y * 128, n0 = blockIdx.x * 128;
  int kbeg = blockIdx.z * Kc;
  float* C = P + (size_t)blockIdx.z * m * m;
  f32x4_t acc[4][4];
#pragma unroll
  for (int i = 0; i < 4; i++)
#pragma unroll
    for (int j = 0; j < 4; j++) acc[i][j] = (f32x4_t){0.f, 0.f, 0.f, 0.f};

  int srow = tid & 127, scp = tid >> 7;
  int pa = perm[m0 + srow];
  int pb = perm[n0 + srow];
  const float* Ag = S + (size_t)pa * lda + kbeg + scp * 16;
  const float* Bg = ST + (size_t)pb * lda + kbeg + scp * 16;
  int g = srow >> 4, rr = srow & 15;
  int d0 = ((g * 4 + scp * 2) * 16 + rr) * 8;
  int d1 = ((g * 4 + scp * 2 + 1) * 16 + rr) * 8;

  for (int kt = 0; kt < Kc; kt += 32) {
    float a[16], b[16];
    *(float4*)&a[0] = *(const float4*)(Ag + kt);
    *(float4*)&a[4] = *(const float4*)(Ag + kt + 4);
    *(float4*)&a[8] = *(const float4*)(Ag + kt + 8);
    *(float4*)&a[12] = *(const float4*)(Ag + kt + 12);
    *(float4*)&b[0] = *(const float4*)(Bg + kt);
    *(float4*)&b[4] = *(const float4*)(Bg + kt + 4);
    *(float4*)&b[8] = *(const float4*)(Bg + kt + 8);
    *(float4*)&b[12] = *(const float4*)(Bg + kt + 12);
    int cb = kbeg + scp * 16 + kt;
    int da = pa - cb;
    if (da >= 0 && da < 16) a[da] += 1.0f;
    int db = pb - cb;
    if (db >= 0 && db < 16) b[db] += 1.0f;
    __syncthreads();
    short8_t sa, sb;
#pragma unroll
    for (int i = 0; i < 8; i++) sa[i] = (short)(__float_as_uint(a[i]) >> 16);
    *(short8_t*)&As[d0] = sa;
#pragma unroll
    for (int i = 0; i < 8; i++) sa[i] = (short)(__float_as_uint(a[8 + i]) >> 16);
    *(short8_t*)&As[d1] = sa;
#pragma unroll
    for (int i = 0; i < 8; i++) sb[i] = (short)(__float_as_uint(b[i]) >> 16);
    *(short8_t*)&Bs[d0] = sb;
#pragma unroll
    for (int i = 0; i < 8; i++) sb[i] = (short)(__float_as_uint(b[8 + i]) >> 16);
    *(short8_t*)&Bs[d1] = sb;
    __syncthreads();
    short8_t af[4], bf[4];
#pragma unroll
    for (int sm = 0; sm < 4; sm++) af[sm] = *(short8_t*)&As[(((wy * 4 + sm) * 4 + q) * 16 + r) * 8];
#pragma unroll
    for (int sn = 0; sn < 4; sn++) bf[sn] = *(short8_t*)&Bs[(((wx * 4 + sn) * 4 + q) * 16 + r) * 8];
#pragma unroll
    for (int sm = 0; sm < 4; sm++)
#pragma unroll
      for (int sn = 0; sn < 4; sn++)
        acc[sm][sn] = __builtin_amdgcn_mfma_f32_16x16x32_bf16(af[sm], bf[sn], acc[sm][sn], 0, 0, 0);
  }
#pragma unroll
  for (int sm = 0; sm < 4; sm++) {
#pragma unroll
    for (int sn = 0; sn < 4; sn++) {
      int grow = m0 + wy * 64 + sm * 16 + q * 4;
      int gcol = n0 + wx * 64 + sn * 16 + r;
#pragma unroll
      for (int v = 0; v < 4; v++) C[(size_t)(grow + v) * m + gcol] = acc[sm][sn][v];
    }
  }
}

// Tiled transpose D = S^T (n x n fp32)
__global__ void transpose_k(const float* __restrict__ S, float* __restrict__ D, int n) {
  __shared__ float tile[32][33];
  int bx = blockIdx.x * 32, by = blockIdx.y * 32;
  int tx = threadIdx.x, ty = threadIdx.y;
  for (int j = 0; j < 32; j += 8) tile[ty + j][tx] = S[(size_t)(by + ty + j) * n + bx + tx];
  __syncthreads();
  for (int j = 0; j < 32; j += 8) D[(size_t)(bx + ty + j) * n + by + tx] = tile[tx][ty + j];
}

// ---------------------------------------------------------------------------
// Dense propagation, split-K stage: P[z][m][c] = sum_{k in chunk z} A[m][k]*YT[c][k]
__global__ void __launch_bounds__(256) prop_stage_k(const float* __restrict__ A, const float* __restrict__ YT,
                                                    float* __restrict__ P, int M, int N, int K, int Kc) {
  __shared__ float red[4][4][64];
  int tid = threadIdx.x, wid = tid >> 6, lane = tid & 63;
  int kl = lane & 15, cg = lane >> 4;
  int m0 = (blockIdx.x * 4 + wid) * 4;
  int ncb = blockIdx.y * 64;
  int z = blockIdx.z;
  int kbeg = z * Kc, kend = kbeg + Kc;
  float acc[4][16];
#pragma unroll
  for (int r0 = 0; r0 < 4; r0++)
#pragma unroll
    for (int c = 0; c < 16; c++) acc[r0][c] = 0.f;

  for (int k0 = kbeg; k0 < kend; k0 += 64) {
    float4 a4[4];
#pragma unroll
    for (int r0 = 0; r0 < 4; r0++)
      a4[r0] = *(const float4*)(A + (size_t)(m0 + r0) * K + k0 + kl * 4);
#pragma unroll
    for (int c = 0; c < 16; c++) {
      int cc = ncb + cg * 16 + c;
      float4 y4 = *(const float4*)(YT + (size_t)cc * K + k0 + kl * 4);
#pragma unroll
      for (int r0 = 0; r0 < 4; r0++) {
        acc[r0][c] += a4[r0].x * y4.x;
        acc[r0][c] += a4[r0].y * y4.y;
        acc[r0][c] += a4[r0].z * y4.z;
        acc[r0][c] += a4[r0].w * y4.w;
      }
    }
  }
#pragma unroll
  for (int m = 1; m <= 8; m <<= 1)
#pragma unroll
    for (int r0 = 0; r0 < 4; r0++)
#pragma unroll
      for (int c = 0; c < 16; c++)
        acc[r0][c] += __shfl_xor(acc[r0][c], m, 64);
  if (kl == 0) {
#pragma unroll
    for (int r0 = 0; r0 < 4; r0++)
#pragma unroll
      for (int c = 0; c < 16; c++) red[wid][r0][cg * 16 + c] = acc[r0][c];
  }
  __syncthreads();
  int cc = ncb + lane;
#pragma unroll
  for (int r0 = 0; r0 < 4; r0++)
    P[((size_t)z * M + (m0 + r0)) * N + cc] = red[wid][r0][lane];
}

// Reduce split-K partials + GCN epilogue.
__global__ void propred_k(const float* __restrict__ P, const float* __restrict__ YT,
                          float* __restrict__ C, int M, int N, int K, int KS,
                          const float* __restrict__ dinv, const float* __restrict__ fixv,
                          const float* __restrict__ bias, int relu) {
  int t = blockIdx.x * blockDim.x + threadIdx.x;
  if (t >= M * N) return;
  int row = t / N, c = t - row * N;
  float s = 0.f;
  for (int z = 0; z < KS; z++) s += P[((size_t)z * M + row) * N + c];
  s += fixv[row] * YT[(size_t)c * K + row];
  s = s * dinv[row] + bias[c];
  if (relu) s = fmaxf(s, 0.f);
  C[t] = s;
}

// ---------------------------------------------------------------------------
// TopK pooling: scores (norm fused), then fused rank+pool.
__global__ void __launch_bounds__(256) score_k(const float* __restrict__ x, const float* __restrict__ w,
                                               int n, int c, float* __restrict__ s) {
  __shared__ float ws[256];
  __shared__ float red[256];
  __shared__ float nrm;
  int tid = threadIdx.x;
  float t = (tid < c) ? w[tid] : 0.f;
  ws[tid] = t;
  red[tid] = t * t;
  __syncthreads();
  for (int d = 128; d > 0; d >>= 1) {
    if (tid < d) red[tid] += red[tid + d];
    __syncthreads();
  }
  if (tid == 0) nrm = sqrtf(red[0]);
  __syncthreads();
  int i = blockIdx.x * 256 + tid;
  if (i >= n) return;
  const float* xr = x + (size_t)i * c;
  float d = 0.f;
  for (int k = 0; k < c; k++) d += xr[k] * ws[k];
  s[i] = tanhf(d / nrm);
}

// Fused counting-rank + pooled gather: thread i computes its stable descending
// rank r; if r<keep writes perm[r]=i, rankL[i]=r, and xout[r]=x[i]*score.
__global__ void __launch_bounds__(256) rankpool_k(const float* __restrict__ scores,
                                                  const float* __restrict__ x,
                                                  int n, int keep, int c,
                                                  int* __restrict__ perm, int* __restrict__ rankL,
                                                  float* __restrict__ xout) {
  __shared__ float ss[4096];
  int tid = threadIdx.x;
  for (int j = tid; j < n; j += 256) ss[j] = scores[j];
  __syncthreads();
  int i = blockIdx.x * 256 + tid;
  float si = ss[i];
  int r = 0;
  for (int j = 0; j < n; j++) {
    float sj = ss[j];
    r += (sj > si) || (sj == si && j < i);
  }
  if (r < keep) {
    perm[r] = i;
    rankL[i] = r;
    const float* xr = x + (size_t)i * c;
    float* o = xout + (size_t)r * c;
    for (int k = 0; k < c; k++) o[k] = xr[k] * si;
  } else {
    rankL[i] = -1;
  }
}

// ---------------------------------------------------------------------------
// Fused unpool+concat: cat[i] = [res[i], rank[i]>=0 ? cur[rank[i]][:c] : 0]
__global__ void catfull_k(const float* __restrict__ res, const float* __restrict__ cur,
                          const int* __restrict__ rankL, int n, int c, int cw,
                          float* __restrict__ cat) {
  int t = blockIdx.x * blockDim.x + threadIdx.x;
  if (t >= n * 2 * c) return;
  int i = t / (2 * c), j = t - i * 2 * c;
  if (j < c) cat[t] = res[(size_t)i * c + j];
  else {
    int rr = rankL[i];
    cat[t] = (rr >= 0) ? cur[(size_t)rr * cw + (j - c)] : 0.f;
  }
}

// ---------------------------------------------------------------------------
extern "C" void kernel_launch(void* const* d_in, const int* in_sizes, int n_in,
                              void* d_out, int out_size, void* d_ws, size_t ws_size,
                              hipStream_t stream) {
  (void)n_in; (void)out_size; (void)ws_size;
  const float* xin = (const float*)d_in[0];
  const int* ei = (const int*)d_in[1];
  const int E = in_sizes[1] / 2;
  const int* esrc = ei;
  const int* edst = ei + E;
  const float* Wd[5] = {(const float*)d_in[2], (const float*)d_in[4], (const float*)d_in[6],
                        (const float*)d_in[8], (const float*)d_in[10]};
  const float* bd[5] = {(const float*)d_in[3], (const float*)d_in[5], (const float*)d_in[7],
                        (const float*)d_in[9], (const float*)d_in[11]};
  const float* pw[4] = {(const float*)d_in[12], (const float*)d_in[13],
                        (const float*)d_in[14], (const float*)d_in[15]};
  const float* Wu[4] = {(const float*)d_in[16], (const float*)d_in[18],
                        (const float*)d_in[20], (const float*)d_in[22]};
  const float* bu[4] = {(const float*)d_in[17], (const float*)d_in[19],
                        (const float*)d_in[21], (const float*)d_in[23]};
  const float* Wo = (const float*)d_in[24];
  const float* bo = (const float*)d_in[25];
  float* out = (float*)d_out;

  char* p = (char*)d_ws;
  auto bumpf = [&](size_t ne) -> float* { float* r = (float*)p; p += ((ne * 4 + 255) & ~(size_t)255); return r; };
  auto bumpi = [&](size_t ne) -> int* { int* r = (int*)p; p += ((ne * 4 + 255) & ~(size_t)255); return r; };

  float* A1 = bumpf((size_t)2048 * 2048);
  float* A2 = bumpf((size_t)1024 * 1024);
  float* A3 = bumpf((size_t)512 * 512);
  float* A4 = bumpf((size_t)256 * 256);
  float* Pbuf = bumpf((size_t)8 * 1024 * 1024);   // prop/mfma split-K partials (32MB)
  float* A1T = bumpf((size_t)2048 * 2048);        // 16MB
  float* Pbuf2 = bumpf((size_t)4 * 1024 * 1024);  // sgemm split-K partials (16MB)
  float* y = bumpf((size_t)4096 * 64);
  float* YT = bumpf((size_t)4096 * 64);
  float* XS0 = bumpf((size_t)4096 * 32);
  float* XS1 = bumpf((size_t)2048 * 64);
  float* XS2 = bumpf((size_t)1024 * 128);
  float* XS3 = bumpf((size_t)512 * 256);
  float* XA = bumpf((size_t)4096 * 64);
  float* XB = bumpf((size_t)4096 * 32);
  float* scores = bumpf(4096);
  float* dinvL[5];
  float* fixvL[5];
  int nsz[5] = {4096, 2048, 1024, 512, 256};
  for (int i = 0; i < 5; i++) { dinvL[i] = bumpf(nsz[i]); fixvL[i] = bumpf(nsz[i]); }
  int* perm1 = bumpi(2048);
  int* perm2 = bumpi(1024);
  int* perm3 = bumpi(512);
  int* perm4 = bumpi(256);
  int* rank1 = bumpi(4096);
  int* rank2 = bumpi(2048);
  int* rank3 = bumpi(1024);
  int* rank4 = bumpi(512);
  // contiguous zero-init block: cnt | selfc | fill  (3 x 16KB)
  int* cnt = bumpi(4096);
  int* selfc = bumpi(4096);
  int* fill = bumpi(4096);
  int* offb = bumpi(4100);
  int* bys = bumpi((size_t)E);

  // Split-K fp32 GEMM (K>=256), else fused single launch.
  auto sgemm = [&](const float* L, const float* R, float* C, int M, int N, int K,
                   const float* di, const float* bi, int relu, int transC, int ldc) {
    int gx = (N + 63) / 64, tn = 64;
    if (N <= 32) { gx = (N + 31) / 32; tn = 32; }
    int gy = M / 64;
    if (K < 256) {
      dim3 g(gx, gy);
      if (tn == 32) sgemm_k<32><<<g, dim3(256), 0, stream>>>(L, R, C, M, N, K, di, bi, relu, transC, ldc, nullptr, K, nullptr, nullptr);
      else sgemm_k<64><<<g, dim3(256), 0, stream>>>(L, R, C, M, N, K, di, bi, relu, transC, ldc, nullptr, K, nullptr, nullptr);
    } else {
      int KS = K / 16; if (KS > 16) KS = 16;
      while (KS > 1 && gx * gy * KS > 1024) KS >>= 1;
      int Kc = K / KS;
      dim3 g(gx, gy, KS);
      if (tn == 32) sgemm_k<32><<<g, dim3(256), 0, stream>>>(L, R, C, M, N, K, nullptr, nullptr, 0, 0, 0, Pbuf2, Kc, nullptr, nullptr);
      else sgemm_k<64><<<g, dim3(256), 0, stream>>>(L, R, C, M, N, K, nullptr, nullptr, 0, 0, 0, Pbuf2, Kc, nullptr, nullptr);
      sgemmred_k<<<dim3((M * N + WG - 1) / WG), dim3(WG), 0, stream>>>(
          Pbuf2, C, M, N, KS, di, bi, relu, transC, ldc);
    }
  };
  // Pooled augment via perm-indirected fp32 GEMM (aug3/4): out m2 x m2, K = 2*m2.
  auto augsgemm = [&](const float* S, const int* perm, float* Aout, int m2, int K,
                      float* di, float* fx) {
    int gx = m2 / 64, gy = m2 / 64;
    int KS = K / 16; if (KS > 16) KS = 16;
    while (KS > 1 && gx * gy * KS > 1024) KS >>= 1;
    int Kc = K / KS;
    dim3 g(gx, gy, KS);
    sgemm_k<64><<<g, dim3(256), 0, stream>>>(S, S, nullptr, m2, m2, K, nullptr, nullptr, 0, 0, 0,
                                             Pbuf2, Kc, perm, perm);
    mfredrow_k<<<dim3(m2), dim3(WG), 0, stream>>>(Pbuf2, Aout, m2, KS, di, fx);
  };
  auto gcn_dense = [&](const float* A, int n, const float* x, int cin, const float* W, int cout,
                       const float* bi, int relu, float* zout, const float* di, const float* fx,
                       int Kc, int KS) {
    sgemm(x, W, YT, n, cout, cin, di, nullptr, 0, 1, n);  // YT[cout][n] = (di .* xW)^T
    dim3 g(n / 16, cout / 64, KS);
    prop_stage_k<<<g, dim3(256), 0, stream>>>(A, YT, Pbuf, n, cout, n, Kc);
    propred_k<<<dim3((n * cout + WG - 1) / WG), dim3(WG), 0, stream>>>(
        Pbuf, YT, zout, n, cout, n, KS, di, fx, bi, relu);
  };
  auto pool = [&](const float* x, int n, int c, const float* w, int* perm, int* rankL, float* xout) {
    score_k<<<dim3(n / 256), dim3(256), 0, stream>>>(x, w, n, c, scores);
    rankpool_k<<<dim3(n / 256), dim3(256), 0, stream>>>(scores, x, n, n / 2, c, perm, rankL, xout);
  };

  // ---- CSR build ----
  hipMemsetAsync(cnt, 0, 3 * 4096 * 4, stream);
  edgestats_k<<<dim3((E + WG - 1) / WG), dim3(WG), 0, stream>>>(esrc, edst, cnt, selfc, E);
  exscanfin_k<<<dim3(1), dim3(1024), 0, stream>>>(cnt, selfc, offb, dinvL[0], fixvL[0]);
  scatterd_k<<<dim3((E + WG - 1) / WG), dim3(WG), 0, stream>>>(esrc, edst, offb, fill, bys, E);

  // ---- GCN0 (sparse A0) ----
  sgemm(xin, Wd[0], y, 4096, 32, 128, dinvL[0], nullptr, 0, 0, 0);
  spmv_k<1, 0><<<dim3(1024), dim3(256), 0, stream>>>(offb, bys, y, 32, dinvL[0], fixvL[0], bd[0], 1, XS0);

  // ---- pool1 + aug1 (row-centric LDS SpGEMM) ----
  pool(XS0, 4096, 32, pw[0], perm1, rank1, XA);
  aug1row_k<<<dim3(2048), dim3(WG), 0, stream>>>(offb, bys, perm1, rank1, A1, 2048,
                                                 dinvL[1], fixvL[1]);
  gcn_dense(A1, 2048, XA, 32, Wd[1], 64, bd[1], 1, XS1, dinvL[1], fixvL[1], 256, 8);

  // ---- level 2: pool, perm-indirected bf16 MFMA augment, fused reduce+rowsum ----
  pool(XS1, 2048, 64, pw[1], perm2, rank2, XA);
  transpose_k<<<dim3(64, 64), dim3(32, 8), 0, stream>>>(A1, A1T, 2048);
  mfma_ntp_k<<<dim3(8, 8, 8), dim3(256), 0, stream>>>(A1, A1T, perm2, Pbuf, 1024, 2048, 256);
  mfredrow_k<<<dim3(1024), dim3(WG), 0, stream>>>(Pbuf, A2, 1024, 8, dinvL[2], fixvL[2]);
  gcn_dense(A2, 1024, XA, 64, Wd[2], 128, bd[2], 1, XS2, dinvL[2], fixvL[2], 128, 8);

  // ---- level 3 (perm-indirected fp32 augment) ----
  pool(XS2, 1024, 128, pw[2], perm3, rank3, XA);
  augsgemm(A2, perm3, A3, 512, 1024, dinvL[3], fixvL[3]);
  gcn_dense(A3, 512, XA, 128, Wd[3], 256, bd[3], 1, XS3, dinvL[3], fixvL[3], 64, 8);

  // ---- level 4 ----
  pool(XS3, 512, 256, pw[3], perm4, rank4, XA);
  augsgemm(A3, perm4, A4, 256, 512, dinvL[4], fixvL[4]);
  gcn_dense(A4, 256, XA, 256, Wd[4], 512, bd[4], 1, XB, dinvL[4], fixvL[4], 64, 4);

  // ---- up path ----
  catfull_k<<<dim3((512 * 512 + WG - 1) / WG), dim3(WG), 0, stream>>>(XS3, XB, rank4, 512, 256, 512, XA);
  gcn_dense(A3, 512, XA, 512, Wu[0], 256, bu[0], 1, XB, dinvL[3], fixvL[3], 64, 8);

  catfull_k<<<dim3((1024 * 256 + WG - 1) / WG), dim3(WG), 0, stream>>>(XS2, XB, rank3, 1024, 128, 256, XA);
  gcn_dense(A2, 1024, XA, 256, Wu[1], 128, bu[1], 1, XB, dinvL[2], fixvL[2], 128, 8);

  catfull_k<<<dim3((2048 * 128 + WG - 1) / WG), dim3(WG), 0, stream>>>(XS1, XB, rank2, 2048, 64, 128, XA);
  gcn_dense(A1, 2048, XA, 128, Wu[2], 64, bu[2], 1, XB, dinvL[1], fixvL[1], 256, 8);

  catfull_k<<<dim3((4096 * 64 + WG - 1) / WG), dim3(WG), 0, stream>>>(XS0, XB, rank1, 4096, 32, 64, XA);
  sgemm(XA, Wu[3], y, 4096, 32, 64, dinvL[0], nullptr, 0, 0, 0);
  spmv_k<1, 0><<<dim3(1024), dim3(256), 0, stream>>>(offb, bys, y, 32, dinvL[0], fixvL[0], bu[3], 0, XB);

  // ---- final GCN (sparse A0) + fused softmax ----
  sgemm(XB, Wo, y, 4096, 37, 32, dinvL[0], nullptr, 0, 0, 0);
  spmv_k<0, 1><<<dim3(1024), dim3(256), 0, stream>>>(offb, bys, y, 37, dinvL[0], fixvL[0], bo, 0, out);
}

// Round 9
// 689.652 us; speedup vs baseline: 1.3426x; 1.3426x over previous
//
#include <hip/hip_runtime.h>
#include <math.h>
#include <stddef.h>

#define WG 256

typedef short short8_t __attribute__((ext_vector_type(8)));
typedef float f32x4_t __attribute__((ext_vector_type(4)));

// ---------------------------------------------------------------------------
// Edge stats: in-degree (incl self) + self-edge count.
__global__ void edgestats_k(const int* __restrict__ esrc, const int* __restrict__ edst,
                            int* __restrict__ cnt, int* __restrict__ selfc, int E) {
  int e = blockIdx.x * blockDim.x + threadIdx.x;
  if (e >= E) return;
  int s = esrc[e], d = edst[e];
  atomicAdd(&cnt[d], 1);
  if (s == d) atomicAdd(&selfc[d], 1);
}

// Exclusive scan of cnt (4096) + fused level-0 degree finalize.
__global__ void __launch_bounds__(1024) exscanfin_k(const int* __restrict__ cnt,
                                                    const int* __restrict__ selfc,
                                                    int* __restrict__ off,
                                                    float* __restrict__ dinv,
                                                    float* __restrict__ fixv) {
  __shared__ int part[1024];
  int t = threadIdx.x;
  int l[4];
  l[0] = cnt[t * 4]; l[1] = cnt[t * 4 + 1]; l[2] = cnt[t * 4 + 2]; l[3] = cnt[t * 4 + 3];
  int s = l[0] + l[1] + l[2] + l[3];
  part[t] = s;
  __syncthreads();
  for (int d = 1; d < 1024; d <<= 1) {
    int v = part[t];
    int u = (t >= d) ? part[t - d] : 0;
    __syncthreads();
    part[t] = v + u;
    __syncthreads();
  }
  int ex = (t > 0) ? part[t - 1] : 0;
  off[t * 4] = ex;
  off[t * 4 + 1] = ex + l[0];
  off[t * 4 + 2] = ex + l[0] + l[1];
  off[t * 4 + 3] = ex + l[0] + l[1] + l[2];
  if (t == 1023) off[4096] = part[1023];
#pragma unroll
  for (int u = 0; u < 4; u++) {
    int i = t * 4 + u;
    float fx = (selfc[i] == 0) ? 2.0f : 0.0f;
    float deg = (float)l[u] + fx;
    dinv[i] = (deg > 0.f) ? 1.0f / sqrtf(deg) : 0.f;
    fixv[i] = fx;
  }
}

// in-CSR (by dst, incl self)
__global__ void scatterd_k(const int* __restrict__ esrc, const int* __restrict__ edst,
                           const int* __restrict__ off, int* __restrict__ fill,
                           int* __restrict__ bys, int E) {
  int e = blockIdx.x * blockDim.x + threadIdx.x;
  if (e >= E) return;
  int d = edst[e];
  int p = off[d] + atomicAdd(&fill[d], 1);
  bys[p] = esrc[e];
}

// SpMV: Z[d][c] = dinv[d]*(sum y[src][c] + fixv[d]*y[d][c]) + bias[c]
// SMAX: fuse row softmax (N<=64) writing probabilities.
template<int SMALL, int SMAX>
__global__ void __launch_bounds__(256) spmv_k(const int* __restrict__ off, const int* __restrict__ bys,
                                              const float* __restrict__ y, int N,
                                              const float* __restrict__ dinv, const float* __restrict__ fixv,
                                              const float* __restrict__ bias, int relu,
                                              float* __restrict__ Z) {
  int w = threadIdx.x >> 6, l = threadIdx.x & 63;
  int row = blockIdx.x * 4 + w;
  int b0 = off[row], b1 = off[row + 1];
  if (SMALL) {  // N == 32
    int c = l & 31, eh = l >> 5;
    float acc = 0.f;
    for (int e = b0 + eh; e < b1; e += 2) { int s = bys[e]; acc += y[(size_t)s * N + c]; }
    acc += __shfl_xor(acc, 32, 64);
    if (eh == 0) {
      float v = acc + fixv[row] * y[(size_t)row * N + c];
      v = v * dinv[row] + (bias ? bias[c] : 0.f);
      if (relu) v = fmaxf(v, 0.f);
      Z[(size_t)row * N + c] = v;
    }
  } else {
    bool act = l < N;
    float acc = 0.f;
    for (int e = b0; e < b1; e++) { int s = bys[e]; if (act) acc += y[(size_t)s * N + l]; }
    float v = 0.f;
    if (act) {
      v = acc + fixv[row] * y[(size_t)row * N + l];
      v = v * dinv[row] + (bias ? bias[l] : 0.f);
      if (relu) v = fmaxf(v, 0.f);
    }
    if (SMAX) {
      float mv = act ? v : -3.0e38f;
#pragma unroll
      for (int m = 1; m < 64; m <<= 1) mv = fmaxf(mv, __shfl_xor(mv, m, 64));
      float e = act ? expf(v - mv) : 0.f;
      float se = e;
#pragma unroll
      for (int m = 1; m < 64; m <<= 1) se += __shfl_xor(se, m, 64);
      if (act) Z[(size_t)row * N + l] = e / se;
    } else if (act) {
      Z[(size_t)row * N + l] = v;
    }
  }
}

// ---------------------------------------------------------------------------
// aug1, row-centric LDS SpGEMM (exact ints), fused rowsum -> dinv/fixv.
__global__ void __launch_bounds__(256) aug1row_k(
    const int* __restrict__ off, const int* __restrict__ bys,
    const int* __restrict__ perm, const int* __restrict__ rank1,
    float* __restrict__ A1, int m,
    float* __restrict__ dinv, float* __restrict__ fixv) {
  __shared__ float row[2048];
  __shared__ float red[WG];
  int tid = threadIdx.x;
  int rd = blockIdx.x;
  int d = perm[rd];
  for (int i = tid; i < m; i += WG) row[i] = 0.f;
  __syncthreads();
  int b0 = off[d], b1 = off[d + 1];
  int wave = tid >> 6, lane = tid & 63;
  for (int e = b0 + wave; e < b1; e += 4) {
    int k = bys[e];
    if (k == d) continue;
    int o0 = off[k], o1 = off[k + 1];
    for (int t = o0 + lane; t < o1; t += 64) {
      int j = bys[t];
      if (j == k) continue;
      int rj = rank1[j];
      if (rj >= 0) atomicAdd(&row[rj], 1.0f);
    }
  }
  for (int e = b0 + tid; e < b1; e += WG) {
    int j = bys[e];
    if (j == d) continue;
    int rj = rank1[j];
    if (rj >= 0) atomicAdd(&row[rj], 2.0f);
  }
  __syncthreads();
  if (tid == 0) row[rd] = 0.f;
  __syncthreads();
  float s = 0.f;
  float* Ar = A1 + (size_t)rd * m;
  for (int i = tid; i < m; i += WG) { float v = row[i]; s += v; Ar[i] = v; }
  red[tid] = s;
  __syncthreads();
  for (int dd = WG / 2; dd > 0; dd >>= 1) {
    if (tid < dd) red[tid] += red[tid + dd];
    __syncthreads();
  }
  if (tid == 0) {
    dinv[rd] = 1.0f / sqrtf(red[0] + 2.0f);
    fixv[rd] = 2.0f;
  }
}

// ---------------------------------------------------------------------------
// fp32 SGEMM. Fused mode (P==null): row scale/bias/relu, optional transposed
// store. Split-K mode (P!=null): blockIdx.z picks a Kc-chunk, raw partials.
// permL/permR (optional): L row a = S[permL[a]] + I; R col b = S[:,permR[b]] + I
// (square S, row length K). Scalar compares only (no dynamic reg indexing).
template<int TNv>
__global__ void __launch_bounds__(256) sgemm_k(
    const float* __restrict__ L, const float* __restrict__ R, float* __restrict__ C,
    int M, int N, int K,
    const float* __restrict__ dinv, const float* __restrict__ bias, int relu,
    int transC, int ldc, float* __restrict__ P, int Kc,
    const int* __restrict__ permL, const int* __restrict__ permR) {
  const int MN = TNv / 16;
  __shared__ float Ls[16][68];
  __shared__ float Rs[16][TNv];
  int tid = threadIdx.x;
  int tx = tid & 15, ty = tid >> 4;
  int m0 = blockIdx.y * 64;
  int n0 = blockIdx.x * TNv;
  int kbeg = 0, kend = K;
  if (P) { kbeg = blockIdx.z * Kc; kend = kbeg + Kc; }
  float acc[4][MN];
#pragma unroll
  for (int i = 0; i < 4; i++)
#pragma unroll
    for (int j = 0; j < MN; j++) acc[i][j] = 0.f;

  int lk = tid & 15, lm = tid >> 4;
  int rn = tid % TNv, rk = tid / TNv;
  const int KSL = 256 / TNv;

  for (int kt = kbeg; kt < kend; kt += 16) {
#pragma unroll
    for (int r = 0; r < 4; r++) {
      int m = lm + r * 16;
      if (permL) {
        int pr = permL[m0 + m];
        float v = L[(size_t)pr * K + kt + lk];
        if (kt + lk == pr) v += 1.0f;
        Ls[lk][m] = v;
      } else {
        Ls[lk][m] = L[(size_t)(m0 + m) * K + kt + lk];
      }
    }
#pragma unroll
    for (int r = 0; r < 16 / KSL; r++) {
      int k = rk + r * KSL;
      int gn = n0 + rn;
      float v = 0.f;
      if (gn < N) {
        if (permR) {
          int pr = permR[gn];
          v = R[(size_t)(kt + k) * K + pr];
          if (kt + k == pr) v += 1.0f;
        } else {
          v = R[(size_t)(kt + k) * N + gn];
        }
      }
      Rs[k][rn] = v;
    }
    __syncthreads();
#pragma unroll
    for (int k = 0; k < 16; k++) {
      float a[4], b[MN];
#pragma unroll
      for (int i = 0; i < 4; i++) a[i] = Ls[k][ty * 4 + i];
#pragma unroll
      for (int j = 0; j < MN; j++) b[j] = Rs[k][tx * MN + j];
#pragma unroll
      for (int i = 0; i < 4; i++)
#pragma unroll
        for (int j = 0; j < MN; j++) acc[i][j] += a[i] * b[j];
    }
    __syncthreads();
  }
  if (P) {
    float* Pz = P + (size_t)blockIdx.z * M * N;
#pragma unroll
    for (int i = 0; i < 4; i++) {
      int gi = m0 + ty * 4 + i;
#pragma unroll
      for (int j = 0; j < MN; j++) {
        int gj = n0 + tx * MN + j;
        if (gj < N) Pz[(size_t)gi * N + gj] = acc[i][j];
      }
    }
    return;
  }
#pragma unroll
  for (int i = 0; i < 4; i++) {
    int gi = m0 + ty * 4 + i;
#pragma unroll
    for (int j = 0; j < MN; j++) {
      int gj = n0 + tx * MN + j;
      if (gj < N) {
        float v = acc[i][j];
        if (dinv) v *= dinv[gi];
        if (bias) v += bias[gj];
        if (relu) v = fmaxf(v, 0.f);
        if (transC) C[(size_t)gj * ldc + gi] = v;
        else C[(size_t)gi * N + gj] = v;
      }
    }
  }
}

// Elementwise split-K reduce + epilogue (non-square outputs).
__global__ void sgemmred_k(const float* __restrict__ P, float* __restrict__ C,
                           int M, int N, int KS,
                           const float* __restrict__ dinv, const float* __restrict__ bias,
                           int relu, int transC, int ldc) {
  int t = blockIdx.x * blockDim.x + threadIdx.x;
  if (t >= M * N) return;
  int i = t / N, j = t - i * N;
  float s = 0.f;
  for (int z = 0; z < KS; z++) s += P[(size_t)z * M * N + t];
  if (dinv) s *= dinv[i];
  if (bias) s += bias[j];
  if (relu) s = fmaxf(s, 0.f);
  if (transC) C[(size_t)j * ldc + i] = s;
  else C[t] = s;
}

// Row-oriented split-K reduce + zero diag + fused rowsum -> dinv/fixv (square).
__global__ void __launch_bounds__(256) mfredrow_k(const float* __restrict__ P, float* __restrict__ C,
                                                  int n, int KS,
                                                  float* __restrict__ dinv, float* __restrict__ fixv) {
  __shared__ float red[WG];
  int row = blockIdx.x, tid = threadIdx.x;
  float s = 0.f;
  for (int c = tid; c < n; c += WG) {
    float v = 0.f;
    size_t idx = (size_t)row * n + c;
    for (int z = 0; z < KS; z++) v += P[(size_t)z * n * n + idx];
    if (c == row) v = 0.f;
    C[idx] = v;
    s += v;
  }
  red[tid] = s;
  __syncthreads();
  for (int d = WG / 2; d > 0; d >>= 1) {
    if (tid < d) red[tid] += red[tid + d];
    __syncthreads();
  }
  if (tid == 0) {
    dinv[row] = 1.0f / sqrtf(red[0] + 2.0f);
    fixv[row] = 2.0f;
  }
}

// ---------------------------------------------------------------------------
// bf16 MFMA NT GEMM with perm indirection + on-the-fly +I (static-index
// compares only — no scratch), split-K. Exact small ints -> bf16 exact.
__global__ void __launch_bounds__(256) mfma_ntp_k(const float* __restrict__ S,
                                                  const float* __restrict__ ST,
                                                  const int* __restrict__ perm,
                                                  float* __restrict__ P, int m, int lda, int Kc) {
  __shared__ short As[128 * 32];
  __shared__ short Bs[128 * 32];
  int tid = threadIdx.x;
  int w = tid >> 6, l = tid & 63;
  int wy = w >> 1, wx = w & 1;
  int q = l >> 4, r = l & 15;
  int m0 = blockIdx.y * 128, n0 = blockIdx.x * 128;
  int kbeg = blockIdx.z * Kc;
  float* C = P + (size_t)blockIdx.z * m * m;
  f32x4_t acc[4][4];
#pragma unroll
  for (int i = 0; i < 4; i++)
#pragma unroll
    for (int j = 0; j < 4; j++) acc[i][j] = (f32x4_t){0.f, 0.f, 0.f, 0.f};

  int srow = tid & 127, scp = tid >> 7;
  int pa = perm[m0 + srow];
  int pb = perm[n0 + srow];
  const float* Ag = S + (size_t)pa * lda + kbeg + scp * 16;
  const float* Bg = ST + (size_t)pb * lda + kbeg + scp * 16;
  int g = srow >> 4, rr = srow & 15;
  int d0 = ((g * 4 + scp * 2) * 16 + rr) * 8;
  int d1 = ((g * 4 + scp * 2 + 1) * 16 + rr) * 8;

  for (int kt = 0; kt < Kc; kt += 32) {
    float4 a0 = *(const float4*)(Ag + kt), a1 = *(const float4*)(Ag + kt + 4);
    float4 a2 = *(const float4*)(Ag + kt + 8), a3 = *(const float4*)(Ag + kt + 12);
    float4 b0 = *(const float4*)(Bg + kt), b1 = *(const float4*)(Bg + kt + 4);
    float4 b2 = *(const float4*)(Bg + kt + 8), b3 = *(const float4*)(Bg + kt + 12);
    int cb = kbeg + scp * 16 + kt;
    // +I via static-index compares (keeps everything in VGPRs)
    a0.x += (cb + 0 == pa) ? 1.f : 0.f;  a0.y += (cb + 1 == pa) ? 1.f : 0.f;
    a0.z += (cb + 2 == pa) ? 1.f : 0.f;  a0.w += (cb + 3 == pa) ? 1.f : 0.f;
    a1.x += (cb + 4 == pa) ? 1.f : 0.f;  a1.y += (cb + 5 == pa) ? 1.f : 0.f;
    a1.z += (cb + 6 == pa) ? 1.f : 0.f;  a1.w += (cb + 7 == pa) ? 1.f : 0.f;
    a2.x += (cb + 8 == pa) ? 1.f : 0.f;  a2.y += (cb + 9 == pa) ? 1.f : 0.f;
    a2.z += (cb + 10 == pa) ? 1.f : 0.f; a2.w += (cb + 11 == pa) ? 1.f : 0.f;
    a3.x += (cb + 12 == pa) ? 1.f : 0.f; a3.y += (cb + 13 == pa) ? 1.f : 0.f;
    a3.z += (cb + 14 == pa) ? 1.f : 0.f; a3.w += (cb + 15 == pa) ? 1.f : 0.f;
    b0.x += (cb + 0 == pb) ? 1.f : 0.f;  b0.y += (cb + 1 == pb) ? 1.f : 0.f;
    b0.z += (cb + 2 == pb) ? 1.f : 0.f;  b0.w += (cb + 3 == pb) ? 1.f : 0.f;
    b1.x += (cb + 4 == pb) ? 1.f : 0.f;  b1.y += (cb + 5 == pb) ? 1.f : 0.f;
    b1.z += (cb + 6 == pb) ? 1.f : 0.f;  b1.w += (cb + 7 == pb) ? 1.f : 0.f;
    b2.x += (cb + 8 == pb) ? 1.f : 0.f;  b2.y += (cb + 9 == pb) ? 1.f : 0.f;
    b2.z += (cb + 10 == pb) ? 1.f : 0.f; b2.w += (cb + 11 == pb) ? 1.f : 0.f;
    b3.x += (cb + 12 == pb) ? 1.f : 0.f; b3.y += (cb + 13 == pb) ? 1.f : 0.f;
    b3.z += (cb + 14 == pb) ? 1.f : 0.f; b3.w += (cb + 15 == pb) ? 1.f : 0.f;
    __syncthreads();
    short8_t sa, sb;
    sa[0] = (short)(__float_as_uint(a0.x) >> 16); sa[1] = (short)(__float_as_uint(a0.y) >> 16);
    sa[2] = (short)(__float_as_uint(a0.z) >> 16); sa[3] = (short)(__float_as_uint(a0.w) >> 16);
    sa[4] = (short)(__float_as_uint(a1.x) >> 16); sa[5] = (short)(__float_as_uint(a1.y) >> 16);
    sa[6] = (short)(__float_as_uint(a1.z) >> 16); sa[7] = (short)(__float_as_uint(a1.w) >> 16);
    *(short8_t*)&As[d0] = sa;
    sa[0] = (short)(__float_as_uint(a2.x) >> 16); sa[1] = (short)(__float_as_uint(a2.y) >> 16);
    sa[2] = (short)(__float_as_uint(a2.z) >> 16); sa[3] = (short)(__float_as_uint(a2.w) >> 16);
    sa[4] = (short)(__float_as_uint(a3.x) >> 16); sa[5] = (short)(__float_as_uint(a3.y) >> 16);
    sa[6] = (short)(__float_as_uint(a3.z) >> 16); sa[7] = (short)(__float_as_uint(a3.w) >> 16);
    *(short8_t*)&As[d1] = sa;
    sb[0] = (short)(__float_as_uint(b0.x) >> 16); sb[1] = (short)(__float_as_uint(b0.y) >> 16);
    sb[2] = (short)(__float_as_uint(b0.z) >> 16); sb[3] = (short)(__float_as_uint(b0.w) >> 16);
    sb[4] = (short)(__float_as_uint(b1.x) >> 16); sb[5] = (short)(__float_as_uint(b1.y) >> 16);
    sb[6] = (short)(__float_as_uint(b1.z) >> 16); sb[7] = (short)(__float_as_uint(b1.w) >> 16);
    *(short8_t*)&Bs[d0] = sb;
    sb[0] = (short)(__float_as_uint(b2.x) >> 16); sb[1] = (short)(__float_as_uint(b2.y) >> 16);
    sb[2] = (short)(__float_as_uint(b2.z) >> 16); sb[3] = (short)(__float_as_uint(b2.w) >> 16);
    sb[4] = (short)(__float_as_uint(b3.x) >> 16); sb[5] = (short)(__float_as_uint(b3.y) >> 16);
    sb[6] = (short)(__float_as_uint(b3.z) >> 16); sb[7] = (short)(__float_as_uint(b3.w) >> 16);
    *(short8_t*)&Bs[d1] = sb;
    __syncthreads();
    short8_t af[4], bf[4];
#pragma unroll
    for (int sm = 0; sm < 4; sm++) af[sm] = *(short8_t*)&As[(((wy * 4 + sm) * 4 + q) * 16 + r) * 8];
#pragma unroll
    for (int sn = 0; sn < 4; sn++) bf[sn] = *(short8_t*)&Bs[(((wx * 4 + sn) * 4 + q) * 16 + r) * 8];
#pragma unroll
    for (int sm = 0; sm < 4; sm++)
#pragma unroll
      for (int sn = 0; sn < 4; sn++)
        acc[sm][sn] = __builtin_amdgcn_mfma_f32_16x16x32_bf16(af[sm], bf[sn], acc[sm][sn], 0, 0, 0);
  }
#pragma unroll
  for (int sm = 0; sm < 4; sm++) {
#pragma unroll
    for (int sn = 0; sn < 4; sn++) {
      int grow = m0 + wy * 64 + sm * 16 + q * 4;
      int gcol = n0 + wx * 64 + sn * 16 + r;
#pragma unroll
      for (int v = 0; v < 4; v++) C[(size_t)(grow + v) * m + gcol] = acc[sm][sn][v];
    }
  }
}

// Tiled transpose D = S^T (n x n fp32)
__global__ void transpose_k(const float* __restrict__ S, float* __restrict__ D, int n) {
  __shared__ float tile[32][33];
  int bx = blockIdx.x * 32, by = blockIdx.y * 32;
  int tx = threadIdx.x, ty = threadIdx.y;
  for (int j = 0; j < 32; j += 8) tile[ty + j][tx] = S[(size_t)(by + ty + j) * n + bx + tx];
  __syncthreads();
  for (int j = 0; j < 32; j += 8) D[(size_t)(bx + ty + j) * n + by + tx] = tile[tx][ty + j];
}

// ---------------------------------------------------------------------------
// Dense propagation, split-K stage: P[z][m][c] = sum_{k in chunk z} A[m][k]*YT[c][k]
__global__ void __launch_bounds__(256) prop_stage_k(const float* __restrict__ A, const float* __restrict__ YT,
                                                    float* __restrict__ P, int M, int N, int K, int Kc) {
  __shared__ float red[4][4][64];
  int tid = threadIdx.x, wid = tid >> 6, lane = tid & 63;
  int kl = lane & 15, cg = lane >> 4;
  int m0 = (blockIdx.x * 4 + wid) * 4;
  int ncb = blockIdx.y * 64;
  int z = blockIdx.z;
  int kbeg = z * Kc, kend = kbeg + Kc;
  float acc[4][16];
#pragma unroll
  for (int r0 = 0; r0 < 4; r0++)
#pragma unroll
    for (int c = 0; c < 16; c++) acc[r0][c] = 0.f;

  for (int k0 = kbeg; k0 < kend; k0 += 64) {
    float4 a4[4];
#pragma unroll
    for (int r0 = 0; r0 < 4; r0++)
      a4[r0] = *(const float4*)(A + (size_t)(m0 + r0) * K + k0 + kl * 4);
#pragma unroll
    for (int c = 0; c < 16; c++) {
      int cc = ncb + cg * 16 + c;
      float4 y4 = *(const float4*)(YT + (size_t)cc * K + k0 + kl * 4);
#pragma unroll
      for (int r0 = 0; r0 < 4; r0++) {
        acc[r0][c] += a4[r0].x * y4.x;
        acc[r0][c] += a4[r0].y * y4.y;
        acc[r0][c] += a4[r0].z * y4.z;
        acc[r0][c] += a4[r0].w * y4.w;
      }
    }
  }
#pragma unroll
  for (int m = 1; m <= 8; m <<= 1)
#pragma unroll
    for (int r0 = 0; r0 < 4; r0++)
#pragma unroll
      for (int c = 0; c < 16; c++)
        acc[r0][c] += __shfl_xor(acc[r0][c], m, 64);
  if (kl == 0) {
#pragma unroll
    for (int r0 = 0; r0 < 4; r0++)
#pragma unroll
      for (int c = 0; c < 16; c++) red[wid][r0][cg * 16 + c] = acc[r0][c];
  }
  __syncthreads();
  int cc = ncb + lane;
#pragma unroll
  for (int r0 = 0; r0 < 4; r0++)
    P[((size_t)z * M + (m0 + r0)) * N + cc] = red[wid][r0][lane];
}

// Reduce split-K partials + GCN epilogue.
__global__ void propred_k(const float* __restrict__ P, const float* __restrict__ YT,
                          float* __restrict__ C, int M, int N, int K, int KS,
                          const float* __restrict__ dinv, const float* __restrict__ fixv,
                          const float* __restrict__ bias, int relu) {
  int t = blockIdx.x * blockDim.x + threadIdx.x;
  if (t >= M * N) return;
  int row = t / N, c = t - row * N;
  float s = 0.f;
  for (int z = 0; z < KS; z++) s += P[((size_t)z * M + row) * N + c];
  s += fixv[row] * YT[(size_t)c * K + row];
  s = s * dinv[row] + bias[c];
  if (relu) s = fmaxf(s, 0.f);
  C[t] = s;
}

// ---------------------------------------------------------------------------
// TopK pooling: scores (norm fused, zeroes rcnt), 2-D parallel counting-rank,
// finalize, pooled gather. (Proven R5/R6 structure — do not re-fuse.)
__global__ void __launch_bounds__(256) score_k(const float* __restrict__ x, const float* __restrict__ w,
                                               int n, int c, float* __restrict__ s,
                                               int* __restrict__ rcnt) {
  __shared__ float ws[256];
  __shared__ float red[256];
  __shared__ float nrm;
  int tid = threadIdx.x;
  float t = (tid < c) ? w[tid] : 0.f;
  ws[tid] = t;
  red[tid] = t * t;
  __syncthreads();
  for (int d = 128; d > 0; d >>= 1) {
    if (tid < d) red[tid] += red[tid + d];
    __syncthreads();
  }
  if (tid == 0) nrm = sqrtf(red[0]);
  __syncthreads();
  int i = blockIdx.x * 256 + tid;
  if (i >= n) return;
  rcnt[i] = 0;
  const float* xr = x + (size_t)i * c;
  float d = 0.f;
  for (int k = 0; k < c; k++) d += xr[k] * ws[k];
  s[i] = tanhf(d / nrm);
}

__global__ void __launch_bounds__(256) rankcnt_k(const float* __restrict__ scores, int n,
                                                 int* __restrict__ rcnt) {
  __shared__ float sj[256];
  int tid = threadIdx.x;
  int i = blockIdx.x * 256 + tid;
  int j0 = blockIdx.y * 256;
  sj[tid] = scores[j0 + tid];
  float si = scores[i];
  __syncthreads();
  int cnt = 0;
#pragma unroll 8
  for (int t = 0; t < 256; t++) {
    float s = sj[t];
    cnt += (s > si) || (s == si && (j0 + t) < i);
  }
  if (cnt) atomicAdd(&rcnt[i], cnt);
}

__global__ void rankfin_k(const float* __restrict__ scores, const int* __restrict__ rcnt,
                          int n, int keep, int* __restrict__ perm, float* __restrict__ vals,
                          int* __restrict__ rankL) {
  int i = blockIdx.x * blockDim.x + threadIdx.x;
  if (i >= n) return;
  int r = rcnt[i];
  if (r < keep) { perm[r] = i; vals[r] = scores[i]; rankL[i] = r; }
  else rankL[i] = -1;
}

__global__ void poolx_k(const float* __restrict__ x, const int* __restrict__ perm,
                        const float* __restrict__ vals, int keep, int c, float* __restrict__ out) {
  int t = blockIdx.x * blockDim.x + threadIdx.x;
  if (t >= keep * c) return;
  int a = t / c, j = t - a * c;
  out[t] = x[(size_t)perm[a] * c + j] * vals[a];
}

// ---------------------------------------------------------------------------
// Fused unpool+concat: cat[i] = [res[i], rank[i]>=0 ? cur[rank[i]][:c] : 0]
__global__ void catfull_k(const float* __restrict__ res, const float* __restrict__ cur,
                          const int* __restrict__ rankL, int n, int c, int cw,
                          float* __restrict__ cat) {
  int t = blockIdx.x * blockDim.x + threadIdx.x;
  if (t >= n * 2 * c) return;
  int i = t / (2 * c), j = t - i * 2 * c;
  if (j < c) cat[t] = res[(size_t)i * c + j];
  else {
    int rr = rankL[i];
    cat[t] = (rr >= 0) ? cur[(size_t)rr * cw + (j - c)] : 0.f;
  }
}

// ---------------------------------------------------------------------------
extern "C" void kernel_launch(void* const* d_in, const int* in_sizes, int n_in,
                              void* d_out, int out_size, void* d_ws, size_t ws_size,
                              hipStream_t stream) {
  (void)n_in; (void)out_size; (void)ws_size;
  const float* xin = (const float*)d_in[0];
  const int* ei = (const int*)d_in[1];
  const int E = in_sizes[1] / 2;
  const int* esrc = ei;
  const int* edst = ei + E;
  const float* Wd[5] = {(const float*)d_in[2], (const float*)d_in[4], (const float*)d_in[6],
                        (const float*)d_in[8], (const float*)d_in[10]};
  const float* bd[5] = {(const float*)d_in[3], (const float*)d_in[5], (const float*)d_in[7],
                        (const float*)d_in[9], (const float*)d_in[11]};
  const float* pw[4] = {(const float*)d_in[12], (const float*)d_in[13],
                        (const float*)d_in[14], (const float*)d_in[15]};
  const float* Wu[4] = {(const float*)d_in[16], (const float*)d_in[18],
                        (const float*)d_in[20], (const float*)d_in[22]};
  const float* bu[4] = {(const float*)d_in[17], (const float*)d_in[19],
                        (const float*)d_in[21], (const float*)d_in[23]};
  const float* Wo = (const float*)d_in[24];
  const float* bo = (const float*)d_in[25];
  float* out = (float*)d_out;

  char* p = (char*)d_ws;
  auto bumpf = [&](size_t ne) -> float* { float* r = (float*)p; p += ((ne * 4 + 255) & ~(size_t)255); return r; };
  auto bumpi = [&](size_t ne) -> int* { int* r = (int*)p; p += ((ne * 4 + 255) & ~(size_t)255); return r; };

  float* A1 = bumpf((size_t)2048 * 2048);
  float* A2 = bumpf((size_t)1024 * 1024);
  float* A3 = bumpf((size_t)512 * 512);
  float* A4 = bumpf((size_t)256 * 256);
  float* Pbuf = bumpf((size_t)8 * 1024 * 1024);   // prop/mfma split-K partials (32MB)
  float* A1T = bumpf((size_t)2048 * 2048);        // 16MB
  float* Pbuf2 = bumpf((size_t)4 * 1024 * 1024);  // sgemm split-K partials (16MB)
  float* y = bumpf((size_t)4096 * 64);
  float* YT = bumpf((size_t)4096 * 64);
  float* XS0 = bumpf((size_t)4096 * 32);
  float* XS1 = bumpf((size_t)2048 * 64);
  float* XS2 = bumpf((size_t)1024 * 128);
  float* XS3 = bumpf((size_t)512 * 256);
  float* XA = bumpf((size_t)4096 * 64);
  float* XB = bumpf((size_t)4096 * 32);
  float* scores = bumpf(4096);
  float* vals = bumpf(2048);
  float* dinvL[5];
  float* fixvL[5];
  int nsz[5] = {4096, 2048, 1024, 512, 256};
  for (int i = 0; i < 5; i++) { dinvL[i] = bumpf(nsz[i]); fixvL[i] = bumpf(nsz[i]); }
  int* perm1 = bumpi(2048);
  int* perm2 = bumpi(1024);
  int* perm3 = bumpi(512);
  int* perm4 = bumpi(256);
  int* rank1 = bumpi(4096);
  int* rank2 = bumpi(2048);
  int* rank3 = bumpi(1024);
  int* rank4 = bumpi(512);
  // contiguous zero-init block: cnt | selfc | fill  (3 x 16KB)
  int* cnt = bumpi(4096);
  int* selfc = bumpi(4096);
  int* fill = bumpi(4096);
  int* offb = bumpi(4100);
  int* rcnt = bumpi(4096);
  int* bys = bumpi((size_t)E);

  // Split-K fp32 GEMM (K>=256), else fused single launch.
  auto sgemm = [&](const float* L, const float* R, float* C, int M, int N, int K,
                   const float* di, const float* bi, int relu, int transC, int ldc) {
    int gx = (N + 63) / 64, tn = 64;
    if (N <= 32) { gx = (N + 31) / 32; tn = 32; }
    int gy = M / 64;
    if (K < 256) {
      dim3 g(gx, gy);
      if (tn == 32) sgemm_k<32><<<g, dim3(256), 0, stream>>>(L, R, C, M, N, K, di, bi, relu, transC, ldc, nullptr, K, nullptr, nullptr);
      else sgemm_k<64><<<g, dim3(256), 0, stream>>>(L, R, C, M, N, K, di, bi, relu, transC, ldc, nullptr, K, nullptr, nullptr);
    } else {
      int KS = K / 16; if (KS > 16) KS = 16;
      while (KS > 1 && gx * gy * KS > 1024) KS >>= 1;
      int Kc = K / KS;
      dim3 g(gx, gy, KS);
      if (tn == 32) sgemm_k<32><<<g, dim3(256), 0, stream>>>(L, R, C, M, N, K, nullptr, nullptr, 0, 0, 0, Pbuf2, Kc, nullptr, nullptr);
      else sgemm_k<64><<<g, dim3(256), 0, stream>>>(L, R, C, M, N, K, nullptr, nullptr, 0, 0, 0, Pbuf2, Kc, nullptr, nullptr);
      sgemmred_k<<<dim3((M * N + WG - 1) / WG), dim3(WG), 0, stream>>>(
          Pbuf2, C, M, N, KS, di, bi, relu, transC, ldc);
    }
  };
  // Pooled augment via perm-indirected fp32 GEMM (aug3/4): out m2 x m2, K = 2*m2.
  auto augsgemm = [&](const float* S, const int* perm, float* Aout, int m2, int K,
                      float* di, float* fx) {
    int gx = m2 / 64, gy = m2 / 64;
    int KS = K / 16; if (KS > 16) KS = 16;
    while (KS > 1 && gx * gy * KS > 1024) KS >>= 1;
    int Kc = K / KS;
    dim3 g(gx, gy, KS);
    sgemm_k<64><<<g, dim3(256), 0, stream>>>(S, S, nullptr, m2, m2, K, nullptr, nullptr, 0, 0, 0,
                                             Pbuf2, Kc, perm, perm);
    mfredrow_k<<<dim3(m2), dim3(WG), 0, stream>>>(Pbuf2, Aout, m2, KS, di, fx);
  };
  auto gcn_dense = [&](const float* A, int n, const float* x, int cin, const float* W, int cout,
                       const float* bi, int relu, float* zout, const float* di, const float* fx,
                       int Kc, int KS) {
    sgemm(x, W, YT, n, cout, cin, di, nullptr, 0, 1, n);  // YT[cout][n] = (di .* xW)^T
    dim3 g(n / 16, cout / 64, KS);
    prop_stage_k<<<g, dim3(256), 0, stream>>>(A, YT, Pbuf, n, cout, n, Kc);
    propred_k<<<dim3((n * cout + WG - 1) / WG), dim3(WG), 0, stream>>>(
        Pbuf, YT, zout, n, cout, n, KS, di, fx, bi, relu);
  };
  auto pool = [&](const float* x, int n, int c, const float* w, int* perm, int* rankL, float* xout) {
    score_k<<<dim3(n / 256), dim3(256), 0, stream>>>(x, w, n, c, scores, rcnt);
    rankcnt_k<<<dim3(n / 256, n / 256), dim3(256), 0, stream>>>(scores, n, rcnt);
    rankfin_k<<<dim3(n / 256), dim3(256), 0, stream>>>(scores, rcnt, n, n / 2, perm, vals, rankL);
    int keep = n / 2;
    poolx_k<<<dim3((keep * c + WG - 1) / WG), dim3(WG), 0, stream>>>(x, perm, vals, keep, c, xout);
  };

  // ---- CSR build ----
  hipMemsetAsync(cnt, 0, 3 * 4096 * 4, stream);
  edgestats_k<<<dim3((E + WG - 1) / WG), dim3(WG), 0, stream>>>(esrc, edst, cnt, selfc, E);
  exscanfin_k<<<dim3(1), dim3(1024), 0, stream>>>(cnt, selfc, offb, dinvL[0], fixvL[0]);
  scatterd_k<<<dim3((E + WG - 1) / WG), dim3(WG), 0, stream>>>(esrc, edst, offb, fill, bys, E);

  // ---- GCN0 (sparse A0) ----
  sgemm(xin, Wd[0], y, 4096, 32, 128, dinvL[0], nullptr, 0, 0, 0);
  spmv_k<1, 0><<<dim3(1024), dim3(256), 0, stream>>>(offb, bys, y, 32, dinvL[0], fixvL[0], bd[0], 1, XS0);

  // ---- pool1 + aug1 (row-centric LDS SpGEMM) ----
  pool(XS0, 4096, 32, pw[0], perm1, rank1, XA);
  aug1row_k<<<dim3(2048), dim3(WG), 0, stream>>>(offb, bys, perm1, rank1, A1, 2048,
                                                 dinvL[1], fixvL[1]);
  gcn_dense(A1, 2048, XA, 32, Wd[1], 64, bd[1], 1, XS1, dinvL[1], fixvL[1], 256, 8);

  // ---- level 2: pool, perm-indirected bf16 MFMA augment, fused reduce+rowsum ----
  pool(XS1, 2048, 64, pw[1], perm2, rank2, XA);
  transpose_k<<<dim3(64, 64), dim3(32, 8), 0, stream>>>(A1, A1T, 2048);
  mfma_ntp_k<<<dim3(8, 8, 8), dim3(256), 0, stream>>>(A1, A1T, perm2, Pbuf, 1024, 2048, 256);
  mfredrow_k<<<dim3(1024), dim3(WG), 0, stream>>>(Pbuf, A2, 1024, 8, dinvL[2], fixvL[2]);
  gcn_dense(A2, 1024, XA, 64, Wd[2], 128, bd[2], 1, XS2, dinvL[2], fixvL[2], 128, 8);

  // ---- level 3 (perm-indirected fp32 augment) ----
  pool(XS2, 1024, 128, pw[2], perm3, rank3, XA);
  augsgemm(A2, perm3, A3, 512, 1024, dinvL[3], fixvL[3]);
  gcn_dense(A3, 512, XA, 128, Wd[3], 256, bd[3], 1, XS3, dinvL[3], fixvL[3], 64, 8);

  // ---- level 4 ----
  pool(XS3, 512, 256, pw[3], perm4, rank4, XA);
  augsgemm(A3, perm4, A4, 256, 512, dinvL[4], fixvL[4]);
  gcn_dense(A4, 256, XA, 256, Wd[4], 512, bd[4], 1, XB, dinvL[4], fixvL[4], 64, 4);

  // ---- up path ----
  catfull_k<<<dim3((512 * 512 + WG - 1) / WG), dim3(WG), 0, stream>>>(XS3, XB, rank4, 512, 256, 512, XA);
  gcn_dense(A3, 512, XA, 512, Wu[0], 256, bu[0], 1, XB, dinvL[3], fixvL[3], 64, 8);

  catfull_k<<<dim3((1024 * 256 + WG - 1) / WG), dim3(WG), 0, stream>>>(XS2, XB, rank3, 1024, 128, 256, XA);
  gcn_dense(A2, 1024, XA, 256, Wu[1], 128, bu[1], 1, XB, dinvL[2], fixvL[2], 128, 8);

  catfull_k<<<dim3((2048 * 128 + WG - 1) / WG), dim3(WG), 0, stream>>>(XS1, XB, rank2, 2048, 64, 128, XA);
  gcn_dense(A1, 2048, XA, 128, Wu[2], 64, bu[2], 1, XB, dinvL[1], fixvL[1], 256, 8);

  catfull_k<<<dim3((4096 * 64 + WG - 1) / WG), dim3(WG), 0, stream>>>(XS0, XB, rank1, 4096, 32, 64, XA);
  sgemm(XA, Wu[3], y, 4096, 32, 64, dinvL[0], nullptr, 0, 0, 0);
  spmv_k<1, 0><<<dim3(1024), dim3(256), 0, stream>>>(offb, bys, y, 32, dinvL[0], fixvL[0], bu[3], 0, XB);

  // ---- final GCN (sparse A0) + fused softmax ----
  sgemm(XB, Wo, y, 4096, 37, 32, dinvL[0], nullptr, 0, 0, 0);
  spmv_k<0, 1><<<dim3(1024), dim3(256), 0, stream>>>(offb, bys, y, 37, dinvL[0], fixvL[0], bo, 0, out);
}

// Round 10
// 658.000 us; speedup vs baseline: 1.4072x; 1.0481x over previous
//
#include <hip/hip_runtime.h>
#include <math.h>
#include <stddef.h>

#define WG 256

typedef short short8_t __attribute__((ext_vector_type(8)));
typedef float f32x4_t __attribute__((ext_vector_type(4)));

// ---------------------------------------------------------------------------
// Edge stats: in-degree (incl self) + self-edge count.
__global__ void edgestats_k(const int* __restrict__ esrc, const int* __restrict__ edst,
                            int* __restrict__ cnt, int* __restrict__ selfc, int E) {
  int e = blockIdx.x * blockDim.x + threadIdx.x;
  if (e >= E) return;
  int s = esrc[e], d = edst[e];
  atomicAdd(&cnt[d], 1);
  if (s == d) atomicAdd(&selfc[d], 1);
}

// Exclusive scan of cnt (4096) + fused level-0 degree finalize.
__global__ void __launch_bounds__(1024) exscanfin_k(const int* __restrict__ cnt,
                                                    const int* __restrict__ selfc,
                                                    int* __restrict__ off,
                                                    float* __restrict__ dinv,
                                                    float* __restrict__ fixv) {
  __shared__ int part[1024];
  int t = threadIdx.x;
  int l[4];
  l[0] = cnt[t * 4]; l[1] = cnt[t * 4 + 1]; l[2] = cnt[t * 4 + 2]; l[3] = cnt[t * 4 + 3];
  int s = l[0] + l[1] + l[2] + l[3];
  part[t] = s;
  __syncthreads();
  for (int d = 1; d < 1024; d <<= 1) {
    int v = part[t];
    int u = (t >= d) ? part[t - d] : 0;
    __syncthreads();
    part[t] = v + u;
    __syncthreads();
  }
  int ex = (t > 0) ? part[t - 1] : 0;
  off[t * 4] = ex;
  off[t * 4 + 1] = ex + l[0];
  off[t * 4 + 2] = ex + l[0] + l[1];
  off[t * 4 + 3] = ex + l[0] + l[1] + l[2];
  if (t == 1023) off[4096] = part[1023];
#pragma unroll
  for (int u = 0; u < 4; u++) {
    int i = t * 4 + u;
    float fx = (selfc[i] == 0) ? 2.0f : 0.0f;
    float deg = (float)l[u] + fx;
    dinv[i] = (deg > 0.f) ? 1.0f / sqrtf(deg) : 0.f;
    fixv[i] = fx;
  }
}

// in-CSR (by dst, incl self)
__global__ void scatterd_k(const int* __restrict__ esrc, const int* __restrict__ edst,
                           const int* __restrict__ off, int* __restrict__ fill,
                           int* __restrict__ bys, int E) {
  int e = blockIdx.x * blockDim.x + threadIdx.x;
  if (e >= E) return;
  int d = edst[e];
  int p = off[d] + atomicAdd(&fill[d], 1);
  bys[p] = esrc[e];
}

// SpMV: Z[d][c] = dinv[d]*(sum y[src][c] + fixv[d]*y[d][c]) + bias[c]
// SMAX: fuse row softmax (N<=64) writing probabilities.
template<int SMALL, int SMAX>
__global__ void __launch_bounds__(256) spmv_k(const int* __restrict__ off, const int* __restrict__ bys,
                                              const float* __restrict__ y, int N,
                                              const float* __restrict__ dinv, const float* __restrict__ fixv,
                                              const float* __restrict__ bias, int relu,
                                              float* __restrict__ Z) {
  int w = threadIdx.x >> 6, l = threadIdx.x & 63;
  int row = blockIdx.x * 4 + w;
  int b0 = off[row], b1 = off[row + 1];
  if (SMALL) {  // N == 32
    int c = l & 31, eh = l >> 5;
    float acc = 0.f;
    for (int e = b0 + eh; e < b1; e += 2) { int s = bys[e]; acc += y[(size_t)s * N + c]; }
    acc += __shfl_xor(acc, 32, 64);
    if (eh == 0) {
      float v = acc + fixv[row] * y[(size_t)row * N + c];
      v = v * dinv[row] + (bias ? bias[c] : 0.f);
      if (relu) v = fmaxf(v, 0.f);
      Z[(size_t)row * N + c] = v;
    }
  } else {
    bool act = l < N;
    float acc = 0.f;
    for (int e = b0; e < b1; e++) { int s = bys[e]; if (act) acc += y[(size_t)s * N + l]; }
    float v = 0.f;
    if (act) {
      v = acc + fixv[row] * y[(size_t)row * N + l];
      v = v * dinv[row] + (bias ? bias[l] : 0.f);
      if (relu) v = fmaxf(v, 0.f);
    }
    if (SMAX) {
      float mv = act ? v : -3.0e38f;
#pragma unroll
      for (int m = 1; m < 64; m <<= 1) mv = fmaxf(mv, __shfl_xor(mv, m, 64));
      float e = act ? expf(v - mv) : 0.f;
      float se = e;
#pragma unroll
      for (int m = 1; m < 64; m <<= 1) se += __shfl_xor(se, m, 64);
      if (act) Z[(size_t)row * N + l] = e / se;
    } else if (act) {
      Z[(size_t)row * N + l] = v;
    }
  }
}

// ---------------------------------------------------------------------------
// aug1, row-centric LDS SpGEMM (exact ints), fused rowsum -> dinv/fixv.
__global__ void __launch_bounds__(256) aug1row_k(
    const int* __restrict__ off, const int* __restrict__ bys,
    const int* __restrict__ perm, const int* __restrict__ rank1,
    float* __restrict__ A1, int m,
    float* __restrict__ dinv, float* __restrict__ fixv) {
  __shared__ float row[2048];
  __shared__ float red[WG];
  int tid = threadIdx.x;
  int rd = blockIdx.x;
  int d = perm[rd];
  for (int i = tid; i < m; i += WG) row[i] = 0.f;
  __syncthreads();
  int b0 = off[d], b1 = off[d + 1];
  int wave = tid >> 6, lane = tid & 63;
  for (int e = b0 + wave; e < b1; e += 4) {
    int k = bys[e];
    if (k == d) continue;
    int o0 = off[k], o1 = off[k + 1];
    for (int t = o0 + lane; t < o1; t += 64) {
      int j = bys[t];
      if (j == k) continue;
      int rj = rank1[j];
      if (rj >= 0) atomicAdd(&row[rj], 1.0f);
    }
  }
  for (int e = b0 + tid; e < b1; e += WG) {
    int j = bys[e];
    if (j == d) continue;
    int rj = rank1[j];
    if (rj >= 0) atomicAdd(&row[rj], 2.0f);
  }
  __syncthreads();
  if (tid == 0) row[rd] = 0.f;
  __syncthreads();
  float s = 0.f;
  float* Ar = A1 + (size_t)rd * m;
  for (int i = tid; i < m; i += WG) { float v = row[i]; s += v; Ar[i] = v; }
  red[tid] = s;
  __syncthreads();
  for (int dd = WG / 2; dd > 0; dd >>= 1) {
    if (tid < dd) red[tid] += red[tid + dd];
    __syncthreads();
  }
  if (tid == 0) {
    dinv[rd] = 1.0f / sqrtf(red[0] + 2.0f);
    fixv[rd] = 2.0f;
  }
}

// ---------------------------------------------------------------------------
// fp32 SGEMM. Fused mode (P==null): row scale/bias/relu, optional transposed
// store. Split-K mode (P!=null): blockIdx.z picks a Kc-chunk, raw partials.
// cat mode (catRes!=null): L[i][k] = k<catc ? catRes[i][k]
//                                  : (catRank[i]>=0 ? catCur[catRank[i]][k-catc] : 0)
template<int TNv>
__global__ void __launch_bounds__(256) sgemm_k(
    const float* __restrict__ L, const float* __restrict__ R, float* __restrict__ C,
    int M, int N, int K,
    const float* __restrict__ dinv, const float* __restrict__ bias, int relu,
    int transC, int ldc, float* __restrict__ P, int Kc,
    const float* __restrict__ catRes, const float* __restrict__ catCur,
    const int* __restrict__ catRank, int catc, int catw) {
  const int MN = TNv / 16;
  __shared__ float Ls[16][68];
  __shared__ float Rs[16][TNv];
  int tid = threadIdx.x;
  int tx = tid & 15, ty = tid >> 4;
  int m0 = blockIdx.y * 64;
  int n0 = blockIdx.x * TNv;
  int kbeg = 0, kend = K;
  if (P) { kbeg = blockIdx.z * Kc; kend = kbeg + Kc; }
  float acc[4][MN];
#pragma unroll
  for (int i = 0; i < 4; i++)
#pragma unroll
    for (int j = 0; j < MN; j++) acc[i][j] = 0.f;

  int lk = tid & 15, lm = tid >> 4;
  int rn = tid % TNv, rk = tid / TNv;
  const int KSL = 256 / TNv;

  for (int kt = kbeg; kt < kend; kt += 16) {
#pragma unroll
    for (int r = 0; r < 4; r++) {
      int m = lm + r * 16;
      int row = m0 + m;
      int kk = kt + lk;
      float v;
      if (catRes) {
        if (kk < catc) v = catRes[(size_t)row * catc + kk];
        else {
          int rr = catRank[row];
          v = (rr >= 0) ? catCur[(size_t)rr * catw + (kk - catc)] : 0.f;
        }
      } else {
        v = L[(size_t)row * K + kk];
      }
      Ls[lk][m] = v;
    }
#pragma unroll
    for (int r = 0; r < 16 / KSL; r++) {
      int k = rk + r * KSL;
      int gn = n0 + rn;
      Rs[k][rn] = (gn < N) ? R[(size_t)(kt + k) * N + gn] : 0.f;
    }
    __syncthreads();
#pragma unroll
    for (int k = 0; k < 16; k++) {
      float a[4], b[MN];
#pragma unroll
      for (int i = 0; i < 4; i++) a[i] = Ls[k][ty * 4 + i];
#pragma unroll
      for (int j = 0; j < MN; j++) b[j] = Rs[k][tx * MN + j];
#pragma unroll
      for (int i = 0; i < 4; i++)
#pragma unroll
        for (int j = 0; j < MN; j++) acc[i][j] += a[i] * b[j];
    }
    __syncthreads();
  }
  if (P) {
    float* Pz = P + (size_t)blockIdx.z * M * N;
#pragma unroll
    for (int i = 0; i < 4; i++) {
      int gi = m0 + ty * 4 + i;
#pragma unroll
      for (int j = 0; j < MN; j++) {
        int gj = n0 + tx * MN + j;
        if (gj < N) Pz[(size_t)gi * N + gj] = acc[i][j];
      }
    }
    return;
  }
#pragma unroll
  for (int i = 0; i < 4; i++) {
    int gi = m0 + ty * 4 + i;
#pragma unroll
    for (int j = 0; j < MN; j++) {
      int gj = n0 + tx * MN + j;
      if (gj < N) {
        float v = acc[i][j];
        if (dinv) v *= dinv[gi];
        if (bias) v += bias[gj];
        if (relu) v = fmaxf(v, 0.f);
        if (transC) C[(size_t)gj * ldc + gi] = v;
        else C[(size_t)gi * N + gj] = v;
      }
    }
  }
}

// Elementwise split-K reduce + epilogue (non-square outputs).
__global__ void sgemmred_k(const float* __restrict__ P, float* __restrict__ C,
                           int M, int N, int KS,
                           const float* __restrict__ dinv, const float* __restrict__ bias,
                           int relu, int transC, int ldc) {
  int t = blockIdx.x * blockDim.x + threadIdx.x;
  if (t >= M * N) return;
  int i = t / N, j = t - i * N;
  float s = 0.f;
  for (int z = 0; z < KS; z++) s += P[(size_t)z * M * N + t];
  if (dinv) s *= dinv[i];
  if (bias) s += bias[j];
  if (relu) s = fmaxf(s, 0.f);
  if (transC) C[(size_t)j * ldc + i] = s;
  else C[t] = s;
}

// Row-oriented split-K reduce + zero diag + fused rowsum -> dinv/fixv (square).
__global__ void __launch_bounds__(256) mfredrow_k(const float* __restrict__ P, float* __restrict__ C,
                                                  int n, int KS,
                                                  float* __restrict__ dinv, float* __restrict__ fixv) {
  __shared__ float red[WG];
  int row = blockIdx.x, tid = threadIdx.x;
  float s = 0.f;
  for (int c = tid; c < n; c += WG) {
    float v = 0.f;
    size_t idx = (size_t)row * n + c;
    for (int z = 0; z < KS; z++) v += P[(size_t)z * n * n + idx];
    if (c == row) v = 0.f;
    C[idx] = v;
    s += v;
  }
  red[tid] = s;
  __syncthreads();
  for (int d = WG / 2; d > 0; d >>= 1) {
    if (tid < d) red[tid] += red[tid + d];
    __syncthreads();
  }
  if (tid == 0) {
    dinv[row] = 1.0f / sqrtf(red[0] + 2.0f);
    fixv[row] = 2.0f;
  }
}

// ---------------------------------------------------------------------------
// bf16 MFMA NT GEMM with perm indirection + on-the-fly +I (static-index
// compares only — no scratch), split-K. Exact small ints -> bf16 exact.
__global__ void __launch_bounds__(256) mfma_ntp_k(const float* __restrict__ S,
                                                  const float* __restrict__ ST,
                                                  const int* __restrict__ perm,
                                                  float* __restrict__ P, int m, int lda, int Kc) {
  __shared__ short As[128 * 32];
  __shared__ short Bs[128 * 32];
  int tid = threadIdx.x;
  int w = tid >> 6, l = tid & 63;
  int wy = w >> 1, wx = w & 1;
  int q = l >> 4, r = l & 15;
  int m0 = blockIdx.y * 128, n0 = blockIdx.x * 128;
  int kbeg = blockIdx.z * Kc;
  float* C = P + (size_t)blockIdx.z * m * m;
  f32x4_t acc[4][4];
#pragma unroll
  for (int i = 0; i < 4; i++)
#pragma unroll
    for (int j = 0; j < 4; j++) acc[i][j] = (f32x4_t){0.f, 0.f, 0.f, 0.f};

  int srow = tid & 127, scp = tid >> 7;
  int pa = perm[m0 + srow];
  int pb = perm[n0 + srow];
  const float* Ag = S + (size_t)pa * lda + kbeg + scp * 16;
  const float* Bg = ST + (size_t)pb * lda + kbeg + scp * 16;
  int g = srow >> 4, rr = srow & 15;
  int d0 = ((g * 4 + scp * 2) * 16 + rr) * 8;
  int d1 = ((g * 4 + scp * 2 + 1) * 16 + rr) * 8;

  for (int kt = 0; kt < Kc; kt += 32) {
    float4 a0 = *(const float4*)(Ag + kt), a1 = *(const float4*)(Ag + kt + 4);
    float4 a2 = *(const float4*)(Ag + kt + 8), a3 = *(const float4*)(Ag + kt + 12);
    float4 b0 = *(const float4*)(Bg + kt), b1 = *(const float4*)(Bg + kt + 4);
    float4 b2 = *(const float4*)(Bg + kt + 8), b3 = *(const float4*)(Bg + kt + 12);
    int cb = kbeg + scp * 16 + kt;
    a0.x += (cb + 0 == pa) ? 1.f : 0.f;  a0.y += (cb + 1 == pa) ? 1.f : 0.f;
    a0.z += (cb + 2 == pa) ? 1.f : 0.f;  a0.w += (cb + 3 == pa) ? 1.f : 0.f;
    a1.x += (cb + 4 == pa) ? 1.f : 0.f;  a1.y += (cb + 5 == pa) ? 1.f : 0.f;
    a1.z += (cb + 6 == pa) ? 1.f : 0.f;  a1.w += (cb + 7 == pa) ? 1.f : 0.f;
    a2.x += (cb + 8 == pa) ? 1.f : 0.f;  a2.y += (cb + 9 == pa) ? 1.f : 0.f;
    a2.z += (cb + 10 == pa) ? 1.f : 0.f; a2.w += (cb + 11 == pa) ? 1.f : 0.f;
    a3.x += (cb + 12 == pa) ? 1.f : 0.f; a3.y += (cb + 13 == pa) ? 1.f : 0.f;
    a3.z += (cb + 14 == pa) ? 1.f : 0.f; a3.w += (cb + 15 == pa) ? 1.f : 0.f;
    b0.x += (cb + 0 == pb) ? 1.f : 0.f;  b0.y += (cb + 1 == pb) ? 1.f : 0.f;
    b0.z += (cb + 2 == pb) ? 1.f : 0.f;  b0.w += (cb + 3 == pb) ? 1.f : 0.f;
    b1.x += (cb + 4 == pb) ? 1.f : 0.f;  b1.y += (cb + 5 == pb) ? 1.f : 0.f;
    b1.z += (cb + 6 == pb) ? 1.f : 0.f;  b1.w += (cb + 7 == pb) ? 1.f : 0.f;
    b2.x += (cb + 8 == pb) ? 1.f : 0.f;  b2.y += (cb + 9 == pb) ? 1.f : 0.f;
    b2.z += (cb + 10 == pb) ? 1.f : 0.f; b2.w += (cb + 11 == pb) ? 1.f : 0.f;
    b3.x += (cb + 12 == pb) ? 1.f : 0.f; b3.y += (cb + 13 == pb) ? 1.f : 0.f;
    b3.z += (cb + 14 == pb) ? 1.f : 0.f; b3.w += (cb + 15 == pb) ? 1.f : 0.f;
    __syncthreads();
    short8_t sa, sb;
    sa[0] = (short)(__float_as_uint(a0.x) >> 16); sa[1] = (short)(__float_as_uint(a0.y) >> 16);
    sa[2] = (short)(__float_as_uint(a0.z) >> 16); sa[3] = (short)(__float_as_uint(a0.w) >> 16);
    sa[4] = (short)(__float_as_uint(a1.x) >> 16); sa[5] = (short)(__float_as_uint(a1.y) >> 16);
    sa[6] = (short)(__float_as_uint(a1.z) >> 16); sa[7] = (short)(__float_as_uint(a1.w) >> 16);
    *(short8_t*)&As[d0] = sa;
    sa[0] = (short)(__float_as_uint(a2.x) >> 16); sa[1] = (short)(__float_as_uint(a2.y) >> 16);
    sa[2] = (short)(__float_as_uint(a2.z) >> 16); sa[3] = (short)(__float_as_uint(a2.w) >> 16);
    sa[4] = (short)(__float_as_uint(a3.x) >> 16); sa[5] = (short)(__float_as_uint(a3.y) >> 16);
    sa[6] = (short)(__float_as_uint(a3.z) >> 16); sa[7] = (short)(__float_as_uint(a3.w) >> 16);
    *(short8_t*)&As[d1] = sa;
    sb[0] = (short)(__float_as_uint(b0.x) >> 16); sb[1] = (short)(__float_as_uint(b0.y) >> 16);
    sb[2] = (short)(__float_as_uint(b0.z) >> 16); sb[3] = (short)(__float_as_uint(b0.w) >> 16);
    sb[4] = (short)(__float_as_uint(b1.x) >> 16); sb[5] = (short)(__float_as_uint(b1.y) >> 16);
    sb[6] = (short)(__float_as_uint(b1.z) >> 16); sb[7] = (short)(__float_as_uint(b1.w) >> 16);
    *(short8_t*)&Bs[d0] = sb;
    sb[0] = (short)(__float_as_uint(b2.x) >> 16); sb[1] = (short)(__float_as_uint(b2.y) >> 16);
    sb[2] = (short)(__float_as_uint(b2.z) >> 16); sb[3] = (short)(__float_as_uint(b2.w) >> 16);
    sb[4] = (short)(__float_as_uint(b3.x) >> 16); sb[5] = (short)(__float_as_uint(b3.y) >> 16);
    sb[6] = (short)(__float_as_uint(b3.z) >> 16); sb[7] = (short)(__float_as_uint(b3.w) >> 16);
    *(short8_t*)&Bs[d1] = sb;
    __syncthreads();
    short8_t af[4], bf[4];
#pragma unroll
    for (int sm = 0; sm < 4; sm++) af[sm] = *(short8_t*)&As[(((wy * 4 + sm) * 4 + q) * 16 + r) * 8];
#pragma unroll
    for (int sn = 0; sn < 4; sn++) bf[sn] = *(short8_t*)&Bs[(((wx * 4 + sn) * 4 + q) * 16 + r) * 8];
#pragma unroll
    for (int sm = 0; sm < 4; sm++)
#pragma unroll
      for (int sn = 0; sn < 4; sn++)
        acc[sm][sn] = __builtin_amdgcn_mfma_f32_16x16x32_bf16(af[sm], bf[sn], acc[sm][sn], 0, 0, 0);
  }
#pragma unroll
  for (int sm = 0; sm < 4; sm++) {
#pragma unroll
    for (int sn = 0; sn < 4; sn++) {
      int grow = m0 + wy * 64 + sm * 16 + q * 4;
      int gcol = n0 + wx * 64 + sn * 16 + r;
#pragma unroll
      for (int v = 0; v < 4; v++) C[(size_t)(grow + v) * m + gcol] = acc[sm][sn][v];
    }
  }
}

// Tiled transpose D = S^T (n x n fp32)
__global__ void transpose_k(const float* __restrict__ S, float* __restrict__ D, int n) {
  __shared__ float tile[32][33];
  int bx = blockIdx.x * 32, by = blockIdx.y * 32;
  int tx = threadIdx.x, ty = threadIdx.y;
  for (int j = 0; j < 32; j += 8) tile[ty + j][tx] = S[(size_t)(by + ty + j) * n + bx + tx];
  __syncthreads();
  for (int j = 0; j < 32; j += 8) D[(size_t)(bx + ty + j) * n + by + tx] = tile[tx][ty + j];
}

// Row gather + I: out[a][k] = S[perm[a]][k] + (perm[a]==k)
__global__ void gatherL_k(const float* __restrict__ S, const int* __restrict__ perm,
                          int n, int m, float* __restrict__ out) {
  int t = blockIdx.x * blockDim.x + threadIdx.x;
  if (t >= m * n) return;
  int a = t / n, k = t - a * n;
  int pa = perm[a];
  out[t] = S[(size_t)pa * n + k] + ((pa == k) ? 1.0f : 0.0f);
}

// Col gather + I: out[k][b] = S[k][perm[b]] + (k==perm[b])
__global__ void gatherR_k(const float* __restrict__ S, const int* __restrict__ perm,
                          int n, int m, float* __restrict__ out) {
  int t = blockIdx.x * blockDim.x + threadIdx.x;
  if (t >= n * m) return;
  int k = t / m, b = t - k * m;
  int pb = perm[b];
  out[t] = S[(size_t)k * n + pb] + ((k == pb) ? 1.0f : 0.0f);
}

// ---------------------------------------------------------------------------
// Dense propagation, split-K stage: P[z][m][c] = sum_{k in chunk z} A[m][k]*YT[c][k]
__global__ void __launch_bounds__(256) prop_stage_k(const float* __restrict__ A, const float* __restrict__ YT,
                                                    float* __restrict__ P, int M, int N, int K, int Kc) {
  __shared__ float red[4][4][64];
  int tid = threadIdx.x, wid = tid >> 6, lane = tid & 63;
  int kl = lane & 15, cg = lane >> 4;
  int m0 = (blockIdx.x * 4 + wid) * 4;
  int ncb = blockIdx.y * 64;
  int z = blockIdx.z;
  int kbeg = z * Kc, kend = kbeg + Kc;
  float acc[4][16];
#pragma unroll
  for (int r0 = 0; r0 < 4; r0++)
#pragma unroll
    for (int c = 0; c < 16; c++) acc[r0][c] = 0.f;

  for (int k0 = kbeg; k0 < kend; k0 += 64) {
    float4 a4[4];
#pragma unroll
    for (int r0 = 0; r0 < 4; r0++)
      a4[r0] = *(const float4*)(A + (size_t)(m0 + r0) * K + k0 + kl * 4);
#pragma unroll
    for (int c = 0; c < 16; c++) {
      int cc = ncb + cg * 16 + c;
      float4 y4 = *(const float4*)(YT + (size_t)cc * K + k0 + kl * 4);
#pragma unroll
      for (int r0 = 0; r0 < 4; r0++) {
        acc[r0][c] += a4[r0].x * y4.x;
        acc[r0][c] += a4[r0].y * y4.y;
        acc[r0][c] += a4[r0].z * y4.z;
        acc[r0][c] += a4[r0].w * y4.w;
      }
    }
  }
#pragma unroll
  for (int m = 1; m <= 8; m <<= 1)
#pragma unroll
    for (int r0 = 0; r0 < 4; r0++)
#pragma unroll
      for (int c = 0; c < 16; c++)
        acc[r0][c] += __shfl_xor(acc[r0][c], m, 64);
  if (kl == 0) {
#pragma unroll
    for (int r0 = 0; r0 < 4; r0++)
#pragma unroll
      for (int c = 0; c < 16; c++) red[wid][r0][cg * 16 + c] = acc[r0][c];
  }
  __syncthreads();
  int cc = ncb + lane;
#pragma unroll
  for (int r0 = 0; r0 < 4; r0++)
    P[((size_t)z * M + (m0 + r0)) * N + cc] = red[wid][r0][lane];
}

// Reduce split-K partials + GCN epilogue.
__global__ void propred_k(const float* __restrict__ P, const float* __restrict__ YT,
                          float* __restrict__ C, int M, int N, int K, int KS,
                          const float* __restrict__ dinv, const float* __restrict__ fixv,
                          const float* __restrict__ bias, int relu) {
  int t = blockIdx.x * blockDim.x + threadIdx.x;
  if (t >= M * N) return;
  int row = t / N, c = t - row * N;
  float s = 0.f;
  for (int z = 0; z < KS; z++) s += P[((size_t)z * M + row) * N + c];
  s += fixv[row] * YT[(size_t)c * K + row];
  s = s * dinv[row] + bias[c];
  if (relu) s = fmaxf(s, 0.f);
  C[t] = s;
}

// ---------------------------------------------------------------------------
// TopK pooling: scores (norm fused, zeroes rcnt), 2-D parallel counting-rank,
// fused finalize+pool over an n*c grid.
__global__ void __launch_bounds__(256) score_k(const float* __restrict__ x, const float* __restrict__ w,
                                               int n, int c, float* __restrict__ s,
                                               int* __restrict__ rcnt) {
  __shared__ float ws[256];
  __shared__ float red[256];
  __shared__ float nrm;
  int tid = threadIdx.x;
  float t = (tid < c) ? w[tid] : 0.f;
  ws[tid] = t;
  red[tid] = t * t;
  __syncthreads();
  for (int d = 128; d > 0; d >>= 1) {
    if (tid < d) red[tid] += red[tid + d];
    __syncthreads();
  }
  if (tid == 0) nrm = sqrtf(red[0]);
  __syncthreads();
  int i = blockIdx.x * 256 + tid;
  if (i >= n) return;
  rcnt[i] = 0;
  const float* xr = x + (size_t)i * c;
  float d = 0.f;
  for (int k = 0; k < c; k++) d += xr[k] * ws[k];
  s[i] = tanhf(d / nrm);
}

__global__ void __launch_bounds__(256) rankcnt_k(const float* __restrict__ scores, int n,
                                                 int* __restrict__ rcnt) {
  __shared__ float sj[256];
  int tid = threadIdx.x;
  int i = blockIdx.x * 256 + tid;
  int j0 = blockIdx.y * 256;
  sj[tid] = scores[j0 + tid];
  float si = scores[i];
  __syncthreads();
  int cnt = 0;
#pragma unroll 8
  for (int t = 0; t < 256; t++) {
    float s = sj[t];
    cnt += (s > si) || (s == si && (j0 + t) < i);
  }
  if (cnt) atomicAdd(&rcnt[i], cnt);
}

// Fused rank finalize + pooled gather (n*c grid: fully parallel).
__global__ void __launch_bounds__(256) rankpool2_k(const float* __restrict__ scores,
                                                   const int* __restrict__ rcnt,
                                                   const float* __restrict__ x,
                                                   int n, int keep, int c,
                                                   int* __restrict__ perm, int* __restrict__ rankL,
                                                   float* __restrict__ xout) {
  int t = blockIdx.x * blockDim.x + threadIdx.x;
  if (t >= n * c) return;
  int i = t / c, j = t - i * c;
  int r = rcnt[i];
  if (r < keep) {
    if (j == 0) { perm[r] = i; rankL[i] = r; }
    xout[(size_t)r * c + j] = x[t] * scores[i];
  } else if (j == 0) {
    rankL[i] = -1;
  }
}

// ---------------------------------------------------------------------------
extern "C" void kernel_launch(void* const* d_in, const int* in_sizes, int n_in,
                              void* d_out, int out_size, void* d_ws, size_t ws_size,
                              hipStream_t stream) {
  (void)n_in; (void)out_size; (void)ws_size;
  const float* xin = (const float*)d_in[0];
  const int* ei = (const int*)d_in[1];
  const int E = in_sizes[1] / 2;
  const int* esrc = ei;
  const int* edst = ei + E;
  const float* Wd[5] = {(const float*)d_in[2], (const float*)d_in[4], (const float*)d_in[6],
                        (const float*)d_in[8], (const float*)d_in[10]};
  const float* bd[5] = {(const float*)d_in[3], (const float*)d_in[5], (const float*)d_in[7],
                        (const float*)d_in[9], (const float*)d_in[11]};
  const float* pw[4] = {(const float*)d_in[12], (const float*)d_in[13],
                        (const float*)d_in[14], (const float*)d_in[15]};
  const float* Wu[4] = {(const float*)d_in[16], (const float*)d_in[18],
                        (const float*)d_in[20], (const float*)d_in[22]};
  const float* bu[4] = {(const float*)d_in[17], (const float*)d_in[19],
                        (const float*)d_in[21], (const float*)d_in[23]};
  const float* Wo = (const float*)d_in[24];
  const float* bo = (const float*)d_in[25];
  float* out = (float*)d_out;

  char* p = (char*)d_ws;
  auto bumpf = [&](size_t ne) -> float* { float* r = (float*)p; p += ((ne * 4 + 255) & ~(size_t)255); return r; };
  auto bumpi = [&](size_t ne) -> int* { int* r = (int*)p; p += ((ne * 4 + 255) & ~(size_t)255); return r; };

  float* A1 = bumpf((size_t)2048 * 2048);
  float* A2 = bumpf((size_t)1024 * 1024);
  float* A3 = bumpf((size_t)512 * 512);
  float* A4 = bumpf((size_t)256 * 256);
  float* Pbuf = bumpf((size_t)8 * 1024 * 1024);   // prop/mfma split-K partials + aug gathers (32MB)
  float* A1T = bumpf((size_t)2048 * 2048);        // 16MB
  float* Pbuf2 = bumpf((size_t)4 * 1024 * 1024);  // sgemm split-K partials (16MB)
  float* y = bumpf((size_t)4096 * 64);
  float* YT = bumpf((size_t)4096 * 64);
  float* XS0 = bumpf((size_t)4096 * 32);
  float* XS1 = bumpf((size_t)2048 * 64);
  float* XS2 = bumpf((size_t)1024 * 128);
  float* XS3 = bumpf((size_t)512 * 256);
  float* XA = bumpf((size_t)4096 * 64);
  float* XB = bumpf((size_t)4096 * 32);
  float* scores = bumpf(4096);
  float* dinvL[5];
  float* fixvL[5];
  int nsz[5] = {4096, 2048, 1024, 512, 256};
  for (int i = 0; i < 5; i++) { dinvL[i] = bumpf(nsz[i]); fixvL[i] = bumpf(nsz[i]); }
  int* perm1 = bumpi(2048);
  int* perm2 = bumpi(1024);
  int* perm3 = bumpi(512);
  int* perm4 = bumpi(256);
  int* rank1 = bumpi(4096);
  int* rank2 = bumpi(2048);
  int* rank3 = bumpi(1024);
  int* rank4 = bumpi(512);
  int* cnt = bumpi(4096);
  int* selfc = bumpi(4096);
  int* fill = bumpi(4096);
  int* offb = bumpi(4100);
  int* rcnt = bumpi(4096);
  int* bys = bumpi((size_t)E);

  float* GL = Pbuf;                               // aug gather scratch (<=2MB each)
  float* GR = Pbuf + (size_t)1024 * 1024;

  // Split-K fp32 GEMM (K>=256), else fused single launch. Optional cat-L mode.
  auto sgemm = [&](const float* L, const float* R, float* C, int M, int N, int K,
                   const float* di, const float* bi, int relu, int transC, int ldc,
                   const float* cres, const float* ccur, const int* crank, int cc, int cw) {
    int gx = (N + 63) / 64, tn = 64;
    if (N <= 32) { gx = (N + 31) / 32; tn = 32; }
    int gy = M / 64;
    if (K < 256) {
      dim3 g(gx, gy);
      if (tn == 32) sgemm_k<32><<<g, dim3(256), 0, stream>>>(L, R, C, M, N, K, di, bi, relu, transC, ldc, nullptr, K, cres, ccur, crank, cc, cw);
      else sgemm_k<64><<<g, dim3(256), 0, stream>>>(L, R, C, M, N, K, di, bi, relu, transC, ldc, nullptr, K, cres, ccur, crank, cc, cw);
    } else {
      int KS = K / 16; if (KS > 16) KS = 16;
      while (KS > 1 && gx * gy * KS > 1024) KS >>= 1;
      int Kc = K / KS;
      dim3 g(gx, gy, KS);
      if (tn == 32) sgemm_k<32><<<g, dim3(256), 0, stream>>>(L, R, C, M, N, K, nullptr, nullptr, 0, 0, 0, Pbuf2, Kc, cres, ccur, crank, cc, cw);
      else sgemm_k<64><<<g, dim3(256), 0, stream>>>(L, R, C, M, N, K, nullptr, nullptr, 0, 0, 0, Pbuf2, Kc, cres, ccur, crank, cc, cw);
      sgemmred_k<<<dim3((M * N + WG - 1) / WG), dim3(WG), 0, stream>>>(
          Pbuf2, C, M, N, KS, di, bi, relu, transC, ldc);
    }
  };
  // Pooled augment (aug3/4): gather operands once (coalesced-write), split-K
  // sgemm, fused reduce+zero-diag+rowsum.
  auto augsgemm = [&](const float* S, const int* perm, float* Aout, int m2, int K,
                      float* di, float* fx) {
    gatherL_k<<<dim3((m2 * K + WG - 1) / WG), dim3(WG), 0, stream>>>(S, perm, K, m2, GL);
    gatherR_k<<<dim3((K * m2 + WG - 1) / WG), dim3(WG), 0, stream>>>(S, perm, K, m2, GR);
    int gx = m2 / 64, gy = m2 / 64;
    int KS = K / 16; if (KS > 16) KS = 16;
    while (KS > 1 && gx * gy * KS > 1024) KS >>= 1;
    int Kc = K / KS;
    dim3 g(gx, gy, KS);
    sgemm_k<64><<<g, dim3(256), 0, stream>>>(GL, GR, nullptr, m2, m2, K, nullptr, nullptr, 0, 0, 0,
                                             Pbuf2, Kc, nullptr, nullptr, nullptr, 0, 0);
    mfredrow_k<<<dim3(m2), dim3(WG), 0, stream>>>(Pbuf2, Aout, m2, KS, di, fx);
  };
  auto gcn_dense = [&](const float* A, int n, const float* x, int cin, const float* W, int cout,
                       const float* bi, int relu, float* zout, const float* di, const float* fx,
                       int Kc, int KS,
                       const float* cres, const float* ccur, const int* crank, int cc, int cw) {
    sgemm(x, W, YT, n, cout, cin, di, nullptr, 0, 1, n, cres, ccur, crank, cc, cw);
    dim3 g(n / 16, cout / 64, KS);
    prop_stage_k<<<g, dim3(256), 0, stream>>>(A, YT, Pbuf, n, cout, n, Kc);
    propred_k<<<dim3((n * cout + WG - 1) / WG), dim3(WG), 0, stream>>>(
        Pbuf, YT, zout, n, cout, n, KS, di, fx, bi, relu);
  };
  auto pool = [&](const float* x, int n, int c, const float* w, int* perm, int* rankL, float* xout) {
    score_k<<<dim3(n / 256), dim3(256), 0, stream>>>(x, w, n, c, scores, rcnt);
    rankcnt_k<<<dim3(n / 256, n / 256), dim3(256), 0, stream>>>(scores, n, rcnt);
    rankpool2_k<<<dim3((n * c + WG - 1) / WG), dim3(WG), 0, stream>>>(
        scores, rcnt, x, n, n / 2, c, perm, rankL, xout);
  };

  // ---- CSR build ----
  hipMemsetAsync(cnt, 0, 3 * 4096 * 4, stream);
  edgestats_k<<<dim3((E + WG - 1) / WG), dim3(WG), 0, stream>>>(esrc, edst, cnt, selfc, E);
  exscanfin_k<<<dim3(1), dim3(1024), 0, stream>>>(cnt, selfc, offb, dinvL[0], fixvL[0]);
  scatterd_k<<<dim3((E + WG - 1) / WG), dim3(WG), 0, stream>>>(esrc, edst, offb, fill, bys, E);

  // ---- GCN0 (sparse A0) ----
  sgemm(xin, Wd[0], y, 4096, 32, 128, dinvL[0], nullptr, 0, 0, 0, nullptr, nullptr, nullptr, 0, 0);
  spmv_k<1, 0><<<dim3(1024), dim3(256), 0, stream>>>(offb, bys, y, 32, dinvL[0], fixvL[0], bd[0], 1, XS0);

  // ---- pool1 + aug1 (row-centric LDS SpGEMM) ----
  pool(XS0, 4096, 32, pw[0], perm1, rank1, XA);
  aug1row_k<<<dim3(2048), dim3(WG), 0, stream>>>(offb, bys, perm1, rank1, A1, 2048,
                                                 dinvL[1], fixvL[1]);
  gcn_dense(A1, 2048, XA, 32, Wd[1], 64, bd[1], 1, XS1, dinvL[1], fixvL[1], 256, 8,
            nullptr, nullptr, nullptr, 0, 0);

  // ---- level 2: pool, perm-indirected bf16 MFMA augment (KS=4), fused reduce ----
  pool(XS1, 2048, 64, pw[1], perm2, rank2, XA);
  transpose_k<<<dim3(64, 64), dim3(32, 8), 0, stream>>>(A1, A1T, 2048);
  mfma_ntp_k<<<dim3(8, 8, 4), dim3(256), 0, stream>>>(A1, A1T, perm2, Pbuf, 1024, 2048, 512);
  mfredrow_k<<<dim3(1024), dim3(WG), 0, stream>>>(Pbuf, A2, 1024, 4, dinvL[2], fixvL[2]);
  gcn_dense(A2, 1024, XA, 64, Wd[2], 128, bd[2], 1, XS2, dinvL[2], fixvL[2], 128, 8,
            nullptr, nullptr, nullptr, 0, 0);

  // ---- level 3 (gather-based fp32 augment) ----
  pool(XS2, 1024, 128, pw[2], perm3, rank3, XA);
  augsgemm(A2, perm3, A3, 512, 1024, dinvL[3], fixvL[3]);
  gcn_dense(A3, 512, XA, 128, Wd[3], 256, bd[3], 1, XS3, dinvL[3], fixvL[3], 64, 8,
            nullptr, nullptr, nullptr, 0, 0);

  // ---- level 4 ----
  pool(XS3, 512, 256, pw[3], perm4, rank4, XA);
  augsgemm(A3, perm4, A4, 256, 512, dinvL[4], fixvL[4]);
  gcn_dense(A4, 256, XA, 256, Wd[4], 512, bd[4], 1, XB, dinvL[4], fixvL[4], 64, 4,
            nullptr, nullptr, nullptr, 0, 0);

  // ---- up path (concat fused into the xW GEMM via cat-L mode) ----
  gcn_dense(A3, 512, nullptr, 512, Wu[0], 256, bu[0], 1, XB, dinvL[3], fixvL[3], 64, 8,
            XS3, XB, rank4, 256, 512);
  gcn_dense(A2, 1024, nullptr, 256, Wu[1], 128, bu[1], 1, XB, dinvL[2], fixvL[2], 128, 8,
            XS2, XB, rank3, 128, 256);
  gcn_dense(A1, 2048, nullptr, 128, Wu[2], 64, bu[2], 1, XB, dinvL[1], fixvL[1], 256, 8,
            XS1, XB, rank2, 64, 128);
  sgemm(nullptr, Wu[3], y, 4096, 32, 64, dinvL[0], nullptr, 0, 0, 0,
        XS0, XB, rank1, 32, 64);
  spmv_k<1, 0><<<dim3(1024), dim3(256), 0, stream>>>(offb, bys, y, 32, dinvL[0], fixvL[0], bu[3], 0, XB);

  // ---- final GCN (sparse A0) + fused softmax ----
  sgemm(XB, Wo, y, 4096, 37, 32, dinvL[0], nullptr, 0, 0, 0, nullptr, nullptr, nullptr, 0, 0);
  spmv_k<0, 1><<<dim3(1024), dim3(256), 0, stream>>>(offb, bys, y, 37, dinvL[0], fixvL[0], bo, 0, out);
}

// Round 11
// 618.338 us; speedup vs baseline: 1.4975x; 1.0641x over previous
//
#include <hip/hip_runtime.h>
#include <math.h>
#include <stddef.h>

#define WG 256

typedef short short8_t __attribute__((ext_vector_type(8)));
typedef float f32x4_t __attribute__((ext_vector_type(4)));

// ---------------------------------------------------------------------------
__global__ void edgestats_k(const int* __restrict__ esrc, const int* __restrict__ edst,
                            int* __restrict__ cnt, int* __restrict__ selfc, int E) {
  int e = blockIdx.x * blockDim.x + threadIdx.x;
  if (e >= E) return;
  int s = esrc[e], d = edst[e];
  atomicAdd(&cnt[d], 1);
  if (s == d) atomicAdd(&selfc[d], 1);
}

__global__ void __launch_bounds__(1024) exscanfin_k(const int* __restrict__ cnt,
                                                    const int* __restrict__ selfc,
                                                    int* __restrict__ off,
                                                    float* __restrict__ dinv,
                                                    float* __restrict__ fixv) {
  __shared__ int part[1024];
  int t = threadIdx.x;
  int l[4];
  l[0] = cnt[t * 4]; l[1] = cnt[t * 4 + 1]; l[2] = cnt[t * 4 + 2]; l[3] = cnt[t * 4 + 3];
  int s = l[0] + l[1] + l[2] + l[3];
  part[t] = s;
  __syncthreads();
  for (int d = 1; d < 1024; d <<= 1) {
    int v = part[t];
    int u = (t >= d) ? part[t - d] : 0;
    __syncthreads();
    part[t] = v + u;
    __syncthreads();
  }
  int ex = (t > 0) ? part[t - 1] : 0;
  off[t * 4] = ex;
  off[t * 4 + 1] = ex + l[0];
  off[t * 4 + 2] = ex + l[0] + l[1];
  off[t * 4 + 3] = ex + l[0] + l[1] + l[2];
  if (t == 1023) off[4096] = part[1023];
#pragma unroll
  for (int u = 0; u < 4; u++) {
    int i = t * 4 + u;
    float fx = (selfc[i] == 0) ? 2.0f : 0.0f;
    float deg = (float)l[u] + fx;
    dinv[i] = (deg > 0.f) ? 1.0f / sqrtf(deg) : 0.f;
    fixv[i] = fx;
  }
}

__global__ void scatterd_k(const int* __restrict__ esrc, const int* __restrict__ edst,
                           const int* __restrict__ off, int* __restrict__ fill,
                           int* __restrict__ bys, int E) {
  int e = blockIdx.x * blockDim.x + threadIdx.x;
  if (e >= E) return;
  int d = edst[e];
  int p = off[d] + atomicAdd(&fill[d], 1);
  bys[p] = esrc[e];
}

template<int SMALL, int SMAX>
__global__ void __launch_bounds__(256) spmv_k(const int* __restrict__ off, const int* __restrict__ bys,
                                              const float* __restrict__ y, int N,
                                              const float* __restrict__ dinv, const float* __restrict__ fixv,
                                              const float* __restrict__ bias, int relu,
                                              float* __restrict__ Z) {
  int w = threadIdx.x >> 6, l = threadIdx.x & 63;
  int row = blockIdx.x * 4 + w;
  int b0 = off[row], b1 = off[row + 1];
  if (SMALL) {
    int c = l & 31, eh = l >> 5;
    float acc = 0.f;
    for (int e = b0 + eh; e < b1; e += 2) { int s = bys[e]; acc += y[(size_t)s * N + c]; }
    acc += __shfl_xor(acc, 32, 64);
    if (eh == 0) {
      float v = acc + fixv[row] * y[(size_t)row * N + c];
      v = v * dinv[row] + (bias ? bias[c] : 0.f);
      if (relu) v = fmaxf(v, 0.f);
      Z[(size_t)row * N + c] = v;
    }
  } else {
    bool act = l < N;
    float acc = 0.f;
    for (int e = b0; e < b1; e++) { int s = bys[e]; if (act) acc += y[(size_t)s * N + l]; }
    float v = 0.f;
    if (act) {
      v = acc + fixv[row] * y[(size_t)row * N + l];
      v = v * dinv[row] + (bias ? bias[l] : 0.f);
      if (relu) v = fmaxf(v, 0.f);
    }
    if (SMAX) {
      float mv = act ? v : -3.0e38f;
#pragma unroll
      for (int m = 1; m < 64; m <<= 1) mv = fmaxf(mv, __shfl_xor(mv, m, 64));
      float e = act ? expf(v - mv) : 0.f;
      float se = e;
#pragma unroll
      for (int m = 1; m < 64; m <<= 1) se += __shfl_xor(se, m, 64);
      if (act) Z[(size_t)row * N + l] = e / se;
    } else if (act) {
      Z[(size_t)row * N + l] = v;
    }
  }
}

// ---------------------------------------------------------------------------
__global__ void __launch_bounds__(256) aug1row_k(
    const int* __restrict__ off, const int* __restrict__ bys,
    const int* __restrict__ perm, const int* __restrict__ rank1,
    float* __restrict__ A1, int m,
    float* __restrict__ dinv, float* __restrict__ fixv) {
  __shared__ float row[2048];
  __shared__ float red[WG];
  int tid = threadIdx.x;
  int rd = blockIdx.x;
  int d = perm[rd];
  for (int i = tid; i < m; i += WG) row[i] = 0.f;
  __syncthreads();
  int b0 = off[d], b1 = off[d + 1];
  int wave = tid >> 6, lane = tid & 63;
  for (int e = b0 + wave; e < b1; e += 4) {
    int k = bys[e];
    if (k == d) continue;
    int o0 = off[k], o1 = off[k + 1];
    for (int t = o0 + lane; t < o1; t += 64) {
      int j = bys[t];
      if (j == k) continue;
      int rj = rank1[j];
      if (rj >= 0) atomicAdd(&row[rj], 1.0f);
    }
  }
  for (int e = b0 + tid; e < b1; e += WG) {
    int j = bys[e];
    if (j == d) continue;
    int rj = rank1[j];
    if (rj >= 0) atomicAdd(&row[rj], 2.0f);
  }
  __syncthreads();
  if (tid == 0) row[rd] = 0.f;
  __syncthreads();
  float s = 0.f;
  float* Ar = A1 + (size_t)rd * m;
  for (int i = tid; i < m; i += WG) { float v = row[i]; s += v; Ar[i] = v; }
  red[tid] = s;
  __syncthreads();
  for (int dd = WG / 2; dd > 0; dd >>= 1) {
    if (tid < dd) red[tid] += red[tid + dd];
    __syncthreads();
  }
  if (tid == 0) {
    dinv[rd] = 1.0f / sqrtf(red[0] + 2.0f);
    fixv[rd] = 2.0f;
  }
}

// ---------------------------------------------------------------------------
template<int TNv>
__global__ void __launch_bounds__(256) sgemm_k(
    const float* __restrict__ L, const float* __restrict__ R, float* __restrict__ C,
    int M, int N, int K,
    const float* __restrict__ dinv, const float* __restrict__ bias, int relu,
    int transC, int ldc, float* __restrict__ P, int Kc,
    const float* __restrict__ catRes, const float* __restrict__ catCur,
    const int* __restrict__ catRank, int catc, int catw) {
  const int MN = TNv / 16;
  __shared__ float Ls[16][68];
  __shared__ float Rs[16][TNv];
  int tid = threadIdx.x;
  int tx = tid & 15, ty = tid >> 4;
  int m0 = blockIdx.y * 64;
  int n0 = blockIdx.x * TNv;
  int kbeg = 0, kend = K;
  if (P) { kbeg = blockIdx.z * Kc; kend = kbeg + Kc; }
  float acc[4][MN];
#pragma unroll
  for (int i = 0; i < 4; i++)
#pragma unroll
    for (int j = 0; j < MN; j++) acc[i][j] = 0.f;

  int lk = tid & 15, lm = tid >> 4;
  int rn = tid % TNv, rk = tid / TNv;
  const int KSL = 256 / TNv;

  for (int kt = kbeg; kt < kend; kt += 16) {
#pragma unroll
    for (int r = 0; r < 4; r++) {
      int m = lm + r * 16;
      int row = m0 + m;
      int kk = kt + lk;
      float v;
      if (catRes) {
        if (kk < catc) v = catRes[(size_t)row * catc + kk];
        else {
          int rr = catRank[row];
          v = (rr >= 0) ? catCur[(size_t)rr * catw + (kk - catc)] : 0.f;
        }
      } else {
        v = L[(size_t)row * K + kk];
      }
      Ls[lk][m] = v;
    }
#pragma unroll
    for (int r = 0; r < 16 / KSL; r++) {
      int k = rk + r * KSL;
      int gn = n0 + rn;
      Rs[k][rn] = (gn < N) ? R[(size_t)(kt + k) * N + gn] : 0.f;
    }
    __syncthreads();
#pragma unroll
    for (int k = 0; k < 16; k++) {
      float a[4], b[MN];
#pragma unroll
      for (int i = 0; i < 4; i++) a[i] = Ls[k][ty * 4 + i];
#pragma unroll
      for (int j = 0; j < MN; j++) b[j] = Rs[k][tx * MN + j];
#pragma unroll
      for (int i = 0; i < 4; i++)
#pragma unroll
        for (int j = 0; j < MN; j++) acc[i][j] += a[i] * b[j];
    }
    __syncthreads();
  }
  if (P) {
    float* Pz = P + (size_t)blockIdx.z * M * N;
#pragma unroll
    for (int i = 0; i < 4; i++) {
      int gi = m0 + ty * 4 + i;
#pragma unroll
      for (int j = 0; j < MN; j++) {
        int gj = n0 + tx * MN + j;
        if (gj < N) Pz[(size_t)gi * N + gj] = acc[i][j];
      }
    }
    return;
  }
#pragma unroll
  for (int i = 0; i < 4; i++) {
    int gi = m0 + ty * 4 + i;
#pragma unroll
    for (int j = 0; j < MN; j++) {
      int gj = n0 + tx * MN + j;
      if (gj < N) {
        float v = acc[i][j];
        if (dinv) v *= dinv[gi];
        if (bias) v += bias[gj];
        if (relu) v = fmaxf(v, 0.f);
        if (transC) C[(size_t)gj * ldc + gi] = v;
        else C[(size_t)gi * N + gj] = v;
      }
    }
  }
}

__global__ void sgemmred_k(const float* __restrict__ P, float* __restrict__ C,
                           int M, int N, int KS,
                           const float* __restrict__ dinv, const float* __restrict__ bias,
                           int relu, int transC, int ldc) {
  int t = blockIdx.x * blockDim.x + threadIdx.x;
  if (t >= M * N) return;
  int i = t / N, j = t - i * N;
  float s = 0.f;
  for (int z = 0; z < KS; z++) s += P[(size_t)z * M * N + t];
  if (dinv) s *= dinv[i];
  if (bias) s += bias[j];
  if (relu) s = fmaxf(s, 0.f);
  if (transC) C[(size_t)j * ldc + i] = s;
  else C[t] = s;
}

__global__ void __launch_bounds__(256) mfredrow_k(const float* __restrict__ P, float* __restrict__ C,
                                                  int n, int KS,
                                                  float* __restrict__ dinv, float* __restrict__ fixv) {
  __shared__ float red[WG];
  int row = blockIdx.x, tid = threadIdx.x;
  float s = 0.f;
  for (int c = tid; c < n; c += WG) {
    float v = 0.f;
    size_t idx = (size_t)row * n + c;
    for (int z = 0; z < KS; z++) v += P[(size_t)z * n * n + idx];
    if (c == row) v = 0.f;
    C[idx] = v;
    s += v;
  }
  red[tid] = s;
  __syncthreads();
  for (int d = WG / 2; d > 0; d >>= 1) {
    if (tid < d) red[tid] += red[tid + d];
    __syncthreads();
  }
  if (tid == 0) {
    dinv[row] = 1.0f / sqrtf(red[0] + 2.0f);
    fixv[row] = 2.0f;
  }
}

// ---------------------------------------------------------------------------
__global__ void __launch_bounds__(256) mfma_ntp_k(const float* __restrict__ S,
                                                  const float* __restrict__ ST,
                                                  const int* __restrict__ perm,
                                                  float* __restrict__ P, int m, int lda, int Kc) {
  __shared__ short As[128 * 32];
  __shared__ short Bs[128 * 32];
  int tid = threadIdx.x;
  int w = tid >> 6, l = tid & 63;
  int wy = w >> 1, wx = w & 1;
  int q = l >> 4, r = l & 15;
  int m0 = blockIdx.y * 128, n0 = blockIdx.x * 128;
  int kbeg = blockIdx.z * Kc;
  float* C = P + (size_t)blockIdx.z * m * m;
  f32x4_t acc[4][4];
#pragma unroll
  for (int i = 0; i < 4; i++)
#pragma unroll
    for (int j = 0; j < 4; j++) acc[i][j] = (f32x4_t){0.f, 0.f, 0.f, 0.f};

  int srow = tid & 127, scp = tid >> 7;
  int pa = perm[m0 + srow];
  int pb = perm[n0 + srow];
  const float* Ag = S + (size_t)pa * lda + kbeg + scp * 16;
  const float* Bg = ST + (size_t)pb * lda + kbeg + scp * 16;
  int g = srow >> 4, rr = srow & 15;
  int d0 = ((g * 4 + scp * 2) * 16 + rr) * 8;
  int d1 = ((g * 4 + scp * 2 + 1) * 16 + rr) * 8;

  for (int kt = 0; kt < Kc; kt += 32) {
    float4 a0 = *(const float4*)(Ag + kt), a1 = *(const float4*)(Ag + kt + 4);
    float4 a2 = *(const float4*)(Ag + kt + 8), a3 = *(const float4*)(Ag + kt + 12);
    float4 b0 = *(const float4*)(Bg + kt), b1 = *(const float4*)(Bg + kt + 4);
    float4 b2 = *(const float4*)(Bg + kt + 8), b3 = *(const float4*)(Bg + kt + 12);
    int cb = kbeg + scp * 16 + kt;
    a0.x += (cb + 0 == pa) ? 1.f : 0.f;  a0.y += (cb + 1 == pa) ? 1.f : 0.f;
    a0.z += (cb + 2 == pa) ? 1.f : 0.f;  a0.w += (cb + 3 == pa) ? 1.f : 0.f;
    a1.x += (cb + 4 == pa) ? 1.f : 0.f;  a1.y += (cb + 5 == pa) ? 1.f : 0.f;
    a1.z += (cb + 6 == pa) ? 1.f : 0.f;  a1.w += (cb + 7 == pa) ? 1.f : 0.f;
    a2.x += (cb + 8 == pa) ? 1.f : 0.f;  a2.y += (cb + 9 == pa) ? 1.f : 0.f;
    a2.z += (cb + 10 == pa) ? 1.f : 0.f; a2.w += (cb + 11 == pa) ? 1.f : 0.f;
    a3.x += (cb + 12 == pa) ? 1.f : 0.f; a3.y += (cb + 13 == pa) ? 1.f : 0.f;
    a3.z += (cb + 14 == pa) ? 1.f : 0.f; a3.w += (cb + 15 == pa) ? 1.f : 0.f;
    b0.x += (cb + 0 == pb) ? 1.f : 0.f;  b0.y += (cb + 1 == pb) ? 1.f : 0.f;
    b0.z += (cb + 2 == pb) ? 1.f : 0.f;  b0.w += (cb + 3 == pb) ? 1.f : 0.f;
    b1.x += (cb + 4 == pb) ? 1.f : 0.f;  b1.y += (cb + 5 == pb) ? 1.f : 0.f;
    b1.z += (cb + 6 == pb) ? 1.f : 0.f;  b1.w += (cb + 7 == pb) ? 1.f : 0.f;
    b2.x += (cb + 8 == pb) ? 1.f : 0.f;  b2.y += (cb + 9 == pb) ? 1.f : 0.f;
    b2.z += (cb + 10 == pb) ? 1.f : 0.f; b2.w += (cb + 11 == pb) ? 1.f : 0.f;
    b3.x += (cb + 12 == pb) ? 1.f : 0.f; b3.y += (cb + 13 == pb) ? 1.f : 0.f;
    b3.z += (cb + 14 == pb) ? 1.f : 0.f; b3.w += (cb + 15 == pb) ? 1.f : 0.f;
    __syncthreads();
    short8_t sa, sb;
    sa[0] = (short)(__float_as_uint(a0.x) >> 16); sa[1] = (short)(__float_as_uint(a0.y) >> 16);
    sa[2] = (short)(__float_as_uint(a0.z) >> 16); sa[3] = (short)(__float_as_uint(a0.w) >> 16);
    sa[4] = (short)(__float_as_uint(a1.x) >> 16); sa[5] = (short)(__float_as_uint(a1.y) >> 16);
    sa[6] = (short)(__float_as_uint(a1.z) >> 16); sa[7] = (short)(__float_as_uint(a1.w) >> 16);
    *(short8_t*)&As[d0] = sa;
    sa[0] = (short)(__float_as_uint(a2.x) >> 16); sa[1] = (short)(__float_as_uint(a2.y) >> 16);
    sa[2] = (short)(__float_as_uint(a2.z) >> 16); sa[3] = (short)(__float_as_uint(a2.w) >> 16);
    sa[4] = (short)(__float_as_uint(a3.x) >> 16); sa[5] = (short)(__float_as_uint(a3.y) >> 16);
    sa[6] = (short)(__float_as_uint(a3.z) >> 16); sa[7] = (short)(__float_as_uint(a3.w) >> 16);
    *(short8_t*)&As[d1] = sa;
    sb[0] = (short)(__float_as_uint(b0.x) >> 16); sb[1] = (short)(__float_as_uint(b0.y) >> 16);
    sb[2] = (short)(__float_as_uint(b0.z) >> 16); sb[3] = (short)(__float_as_uint(b0.w) >> 16);
    sb[4] = (short)(__float_as_uint(b1.x) >> 16); sb[5] = (short)(__float_as_uint(b1.y) >> 16);
    sb[6] = (short)(__float_as_uint(b1.z) >> 16); sb[7] = (short)(__float_as_uint(b1.w) >> 16);
    *(short8_t*)&Bs[d0] = sb;
    sb[0] = (short)(__float_as_uint(b2.x) >> 16); sb[1] = (short)(__float_as_uint(b2.y) >> 16);
    sb[2] = (short)(__float_as_uint(b2.z) >> 16); sb[3] = (short)(__float_as_uint(b2.w) >> 16);
    sb[4] = (short)(__float_as_uint(b3.x) >> 16); sb[5] = (short)(__float_as_uint(b3.y) >> 16);
    sb[6] = (short)(__float_as_uint(b3.z) >> 16); sb[7] = (short)(__float_as_uint(b3.w) >> 16);
    *(short8_t*)&Bs[d1] = sb;
    __syncthreads();
    short8_t af[4], bf[4];
#pragma unroll
    for (int sm = 0; sm < 4; sm++) af[sm] = *(short8_t*)&As[(((wy * 4 + sm) * 4 + q) * 16 + r) * 8];
#pragma unroll
    for (int sn = 0; sn < 4; sn++) bf[sn] = *(short8_t*)&Bs[(((wx * 4 + sn) * 4 + q) * 16 + r) * 8];
#pragma unroll
    for (int sm = 0; sm < 4; sm++)
#pragma unroll
      for (int sn = 0; sn < 4; sn++)
        acc[sm][sn] = __builtin_amdgcn_mfma_f32_16x16x32_bf16(af[sm], bf[sn], acc[sm][sn], 0, 0, 0);
  }
#pragma unroll
  for (int sm = 0; sm < 4; sm++) {
#pragma unroll
    for (int sn = 0; sn < 4; sn++) {
      int grow = m0 + wy * 64 + sm * 16 + q * 4;
      int gcol = n0 + wx * 64 + sn * 16 + r;
#pragma unroll
      for (int v = 0; v < 4; v++) C[(size_t)(grow + v) * m + gcol] = acc[sm][sn][v];
    }
  }
}

__global__ void transpose_k(const float* __restrict__ S, float* __restrict__ D, int n) {
  __shared__ float tile[32][33];
  int bx = blockIdx.x * 32, by = blockIdx.y * 32;
  int tx = threadIdx.x, ty = threadIdx.y;
  for (int j = 0; j < 32; j += 8) tile[ty + j][tx] = S[(size_t)(by + ty + j) * n + bx + tx];
  __syncthreads();
  for (int j = 0; j < 32; j += 8) D[(size_t)(bx + ty + j) * n + by + tx] = tile[tx][ty + j];
}

// Fused L/R gather + I in one launch: first m*n threads -> GL, next n*m -> GR.
__global__ void gatherLR_k(const float* __restrict__ S, const int* __restrict__ perm,
                           int n, int m, float* __restrict__ GL, float* __restrict__ GR) {
  int t = blockIdx.x * blockDim.x + threadIdx.x;
  int half = m * n;
  if (t < half) {
    int a = t / n, k = t - a * n;
    int pa = perm[a];
    GL[t] = S[(size_t)pa * n + k] + ((pa == k) ? 1.0f : 0.0f);
  } else if (t < 2 * half) {
    int u = t - half;
    int k = u / m, b = u - k * m;
    int pb = perm[b];
    GR[u] = S[(size_t)k * n + pb] + ((k == pb) ? 1.0f : 0.0f);
  }
}

// ---------------------------------------------------------------------------
__global__ void __launch_bounds__(256) prop_stage_k(const float* __restrict__ A, const float* __restrict__ YT,
                                                    float* __restrict__ P, int M, int N, int K, int Kc) {
  __shared__ float red[4][4][64];
  int tid = threadIdx.x, wid = tid >> 6, lane = tid & 63;
  int kl = lane & 15, cg = lane >> 4;
  int m0 = (blockIdx.x * 4 + wid) * 4;
  int ncb = blockIdx.y * 64;
  int z = blockIdx.z;
  int kbeg = z * Kc, kend = kbeg + Kc;
  float acc[4][16];
#pragma unroll
  for (int r0 = 0; r0 < 4; r0++)
#pragma unroll
    for (int c = 0; c < 16; c++) acc[r0][c] = 0.f;

  for (int k0 = kbeg; k0 < kend; k0 += 64) {
    float4 a4[4];
#pragma unroll
    for (int r0 = 0; r0 < 4; r0++)
      a4[r0] = *(const float4*)(A + (size_t)(m0 + r0) * K + k0 + kl * 4);
#pragma unroll
    for (int c = 0; c < 16; c++) {
      int cc = ncb + cg * 16 + c;
      float4 y4 = *(const float4*)(YT + (size_t)cc * K + k0 + kl * 4);
#pragma unroll
      for (int r0 = 0; r0 < 4; r0++) {
        acc[r0][c] += a4[r0].x * y4.x;
        acc[r0][c] += a4[r0].y * y4.y;
        acc[r0][c] += a4[r0].z * y4.z;
        acc[r0][c] += a4[r0].w * y4.w;
      }
    }
  }
#pragma unroll
  for (int m = 1; m <= 8; m <<= 1)
#pragma unroll
    for (int r0 = 0; r0 < 4; r0++)
#pragma unroll
      for (int c = 0; c < 16; c++)
        acc[r0][c] += __shfl_xor(acc[r0][c], m, 64);
  if (kl == 0) {
#pragma unroll
    for (int r0 = 0; r0 < 4; r0++)
#pragma unroll
      for (int c = 0; c < 16; c++) red[wid][r0][cg * 16 + c] = acc[r0][c];
  }
  __syncthreads();
  int cc = ncb + lane;
#pragma unroll
  for (int r0 = 0; r0 < 4; r0++)
    P[((size_t)z * M + (m0 + r0)) * N + cc] = red[wid][r0][lane];
}

__global__ void propred_k(const float* __restrict__ P, const float* __restrict__ YT,
                          float* __restrict__ C, int M, int N, int K, int KS,
                          const float* __restrict__ dinv, const float* __restrict__ fixv,
                          const float* __restrict__ bias, int relu) {
  int t = blockIdx.x * blockDim.x + threadIdx.x;
  if (t >= M * N) return;
  int row = t / N, c = t - row * N;
  float s = 0.f;
  for (int z = 0; z < KS; z++) s += P[((size_t)z * M + row) * N + c];
  s += fixv[row] * YT[(size_t)c * K + row];
  s = s * dinv[row] + bias[c];
  if (relu) s = fmaxf(s, 0.f);
  C[t] = s;
}

// ---------------------------------------------------------------------------
__global__ void __launch_bounds__(256) score_k(const float* __restrict__ x, const float* __restrict__ w,
                                               int n, int c, float* __restrict__ s,
                                               int* __restrict__ rcnt) {
  __shared__ float ws[256];
  __shared__ float red[256];
  __shared__ float nrm;
  int tid = threadIdx.x;
  float t = (tid < c) ? w[tid] : 0.f;
  ws[tid] = t;
  red[tid] = t * t;
  __syncthreads();
  for (int d = 128; d > 0; d >>= 1) {
    if (tid < d) red[tid] += red[tid + d];
    __syncthreads();
  }
  if (tid == 0) nrm = sqrtf(red[0]);
  __syncthreads();
  int i = blockIdx.x * 256 + tid;
  if (i >= n) return;
  rcnt[i] = 0;
  const float* xr = x + (size_t)i * c;
  float d = 0.f;
  for (int k = 0; k < c; k++) d += xr[k] * ws[k];
  s[i] = tanhf(d / nrm);
}

__global__ void __launch_bounds__(256) rankcnt_k(const float* __restrict__ scores, int n,
                                                 int* __restrict__ rcnt) {
  __shared__ float sj[256];
  int tid = threadIdx.x;
  int i = blockIdx.x * 256 + tid;
  int j0 = blockIdx.y * 256;
  sj[tid] = scores[j0 + tid];
  float si = scores[i];
  __syncthreads();
  int cnt = 0;
#pragma unroll 8
  for (int t = 0; t < 256; t++) {
    float s = sj[t];
    cnt += (s > si) || (s == si && (j0 + t) < i);
  }
  if (cnt) atomicAdd(&rcnt[i], cnt);
}

__global__ void __launch_bounds__(256) rankpool2_k(const float* __restrict__ scores,
                                                   const int* __restrict__ rcnt,
                                                   const float* __restrict__ x,
                                                   int n, int keep, int c,
                                                   int* __restrict__ perm, int* __restrict__ rankL,
                                                   float* __restrict__ xout) {
  int t = blockIdx.x * blockDim.x + threadIdx.x;
  if (t >= n * c) return;
  int i = t / c, j = t - i * c;
  int r = rcnt[i];
  if (r < keep) {
    if (j == 0) { perm[r] = i; rankL[i] = r; }
    xout[(size_t)r * c + j] = x[t] * scores[i];
  } else if (j == 0) {
    rankL[i] = -1;
  }
}

// ---------------------------------------------------------------------------
extern "C" void kernel_launch(void* const* d_in, const int* in_sizes, int n_in,
                              void* d_out, int out_size, void* d_ws, size_t ws_size,
                              hipStream_t stream) {
  (void)n_in; (void)out_size; (void)ws_size;
  const float* xin = (const float*)d_in[0];
  const int* ei = (const int*)d_in[1];
  const int E = in_sizes[1] / 2;
  const int* esrc = ei;
  const int* edst = ei + E;
  const float* Wd[5] = {(const float*)d_in[2], (const float*)d_in[4], (const float*)d_in[6],
                        (const float*)d_in[8], (const float*)d_in[10]};
  const float* bd[5] = {(const float*)d_in[3], (const float*)d_in[5], (const float*)d_in[7],
                        (const float*)d_in[9], (const float*)d_in[11]};
  const float* pw[4] = {(const float*)d_in[12], (const float*)d_in[13],
                        (const float*)d_in[14], (const float*)d_in[15]};
  const float* Wu[4] = {(const float*)d_in[16], (const float*)d_in[18],
                        (const float*)d_in[20], (const float*)d_in[22]};
  const float* bu[4] = {(const float*)d_in[17], (const float*)d_in[19],
                        (const float*)d_in[21], (const float*)d_in[23]};
  const float* Wo = (const float*)d_in[24];
  const float* bo = (const float*)d_in[25];
  float* out = (float*)d_out;

  char* p = (char*)d_ws;
  auto bumpf = [&](size_t ne) -> float* { float* r = (float*)p; p += ((ne * 4 + 255) & ~(size_t)255); return r; };
  auto bumpi = [&](size_t ne) -> int* { int* r = (int*)p; p += ((ne * 4 + 255) & ~(size_t)255); return r; };

  float* A1 = bumpf((size_t)2048 * 2048);
  float* A2 = bumpf((size_t)1024 * 1024);
  float* A3 = bumpf((size_t)512 * 512);
  float* A4 = bumpf((size_t)256 * 256);
  float* Pbuf = bumpf((size_t)8 * 1024 * 1024);   // prop/mfma split-K partials + aug gathers (32MB)
  float* A1T = bumpf((size_t)2048 * 2048);        // 16MB
  float* Pbuf2 = bumpf((size_t)4 * 1024 * 1024);  // sgemm split-K partials (16MB)
  float* y = bumpf((size_t)4096 * 64);
  float* YT = bumpf((size_t)4096 * 64);
  float* XS0 = bumpf((size_t)4096 * 32);
  float* XS1 = bumpf((size_t)2048 * 64);
  float* XS2 = bumpf((size_t)1024 * 128);
  float* XS3 = bumpf((size_t)512 * 256);
  float* XA = bumpf((size_t)4096 * 64);
  float* XB = bumpf((size_t)4096 * 32);
  float* scores = bumpf(4096);
  float* dinvL[5];
  float* fixvL[5];
  int nsz[5] = {4096, 2048, 1024, 512, 256};
  for (int i = 0; i < 5; i++) { dinvL[i] = bumpf(nsz[i]); fixvL[i] = bumpf(nsz[i]); }
  int* perm1 = bumpi(2048);
  int* perm2 = bumpi(1024);
  int* perm3 = bumpi(512);
  int* perm4 = bumpi(256);
  int* rank1 = bumpi(4096);
  int* rank2 = bumpi(2048);
  int* rank3 = bumpi(1024);
  int* rank4 = bumpi(512);
  int* cnt = bumpi(4096);
  int* selfc = bumpi(4096);
  int* fill = bumpi(4096);
  int* offb = bumpi(4100);
  int* rcnt = bumpi(4096);
  int* bys = bumpi((size_t)E);

  float* GL = Pbuf;
  float* GR = Pbuf + (size_t)1024 * 1024;

  // Split-K policy: split when K>=64, 2 K-iters per block (KS=K/32, cap 16).
  auto sgemm = [&](const float* L, const float* R, float* C, int M, int N, int K,
                   const float* di, const float* bi, int relu, int transC, int ldc,
                   const float* cres, const float* ccur, const int* crank, int cc, int cw) {
    int gx = (N + 63) / 64, tn = 64;
    if (N <= 32) { gx = (N + 31) / 32; tn = 32; }
    int gy = M / 64;
    int KS = (K >= 64) ? K / 32 : 1;
    if (KS > 16) KS = 16;
    while (KS > 1 && (size_t)KS * M * N > (size_t)4 * 1024 * 1024) KS >>= 1;
    if (KS <= 1) {
      dim3 g(gx, gy);
      if (tn == 32) sgemm_k<32><<<g, dim3(256), 0, stream>>>(L, R, C, M, N, K, di, bi, relu, transC, ldc, nullptr, K, cres, ccur, crank, cc, cw);
      else sgemm_k<64><<<g, dim3(256), 0, stream>>>(L, R, C, M, N, K, di, bi, relu, transC, ldc, nullptr, K, cres, ccur, crank, cc, cw);
    } else {
      int Kc = K / KS;
      dim3 g(gx, gy, KS);
      if (tn == 32) sgemm_k<32><<<g, dim3(256), 0, stream>>>(L, R, C, M, N, K, nullptr, nullptr, 0, 0, 0, Pbuf2, Kc, cres, ccur, crank, cc, cw);
      else sgemm_k<64><<<g, dim3(256), 0, stream>>>(L, R, C, M, N, K, nullptr, nullptr, 0, 0, 0, Pbuf2, Kc, cres, ccur, crank, cc, cw);
      sgemmred_k<<<dim3((M * N + WG - 1) / WG), dim3(WG), 0, stream>>>(
          Pbuf2, C, M, N, KS, di, bi, relu, transC, ldc);
    }
  };
  auto augsgemm = [&](const float* S, const int* perm, float* Aout, int m2, int K,
                      float* di, float* fx) {
    gatherLR_k<<<dim3((2 * m2 * K + WG - 1) / WG), dim3(WG), 0, stream>>>(S, perm, K, m2, GL, GR);
    int gx = m2 / 64, gy = m2 / 64;
    int KS = K / 32; if (KS > 16) KS = 16;
    while (KS > 1 && (size_t)KS * m2 * m2 > (size_t)4 * 1024 * 1024) KS >>= 1;
    int Kc = K / KS;
    dim3 g(gx, gy, KS);
    sgemm_k<64><<<g, dim3(256), 0, stream>>>(GL, GR, nullptr, m2, m2, K, nullptr, nullptr, 0, 0, 0,
                                             Pbuf2, Kc, nullptr, nullptr, nullptr, 0, 0);
    mfredrow_k<<<dim3(m2), dim3(WG), 0, stream>>>(Pbuf2, Aout, m2, KS, di, fx);
  };
  auto gcn_dense = [&](const float* A, int n, const float* x, int cin, const float* W, int cout,
                       const float* bi, int relu, float* zout, const float* di, const float* fx,
                       int Kc, int KS,
                       const float* cres, const float* ccur, const int* crank, int cc, int cw) {
    sgemm(x, W, YT, n, cout, cin, di, nullptr, 0, 1, n, cres, ccur, crank, cc, cw);
    dim3 g(n / 16, cout / 64, KS);
    prop_stage_k<<<g, dim3(256), 0, stream>>>(A, YT, Pbuf, n, cout, n, Kc);
    propred_k<<<dim3((n * cout + WG - 1) / WG), dim3(WG), 0, stream>>>(
        Pbuf, YT, zout, n, cout, n, KS, di, fx, bi, relu);
  };
  auto pool = [&](const float* x, int n, int c, const float* w, int* perm, int* rankL, float* xout) {
    score_k<<<dim3(n / 256), dim3(256), 0, stream>>>(x, w, n, c, scores, rcnt);
    rankcnt_k<<<dim3(n / 256, n / 256), dim3(256), 0, stream>>>(scores, n, rcnt);
    rankpool2_k<<<dim3((n * c + WG - 1) / WG), dim3(WG), 0, stream>>>(
        scores, rcnt, x, n, n / 2, c, perm, rankL, xout);
  };

  // ---- CSR build ----
  hipMemsetAsync(cnt, 0, 3 * 4096 * 4, stream);
  edgestats_k<<<dim3((E + WG - 1) / WG), dim3(WG), 0, stream>>>(esrc, edst, cnt, selfc, E);
  exscanfin_k<<<dim3(1), dim3(1024), 0, stream>>>(cnt, selfc, offb, dinvL[0], fixvL[0]);
  scatterd_k<<<dim3((E + WG - 1) / WG), dim3(WG), 0, stream>>>(esrc, edst, offb, fill, bys, E);

  // ---- GCN0 (sparse A0) ----
  sgemm(xin, Wd[0], y, 4096, 32, 128, dinvL[0], nullptr, 0, 0, 0, nullptr, nullptr, nullptr, 0, 0);
  spmv_k<1, 0><<<dim3(1024), dim3(256), 0, stream>>>(offb, bys, y, 32, dinvL[0], fixvL[0], bd[0], 1, XS0);

  // ---- pool1 + aug1 ----
  pool(XS0, 4096, 32, pw[0], perm1, rank1, XA);
  aug1row_k<<<dim3(2048), dim3(WG), 0, stream>>>(offb, bys, perm1, rank1, A1, 2048,
                                                 dinvL[1], fixvL[1]);
  gcn_dense(A1, 2048, XA, 32, Wd[1], 64, bd[1], 1, XS1, dinvL[1], fixvL[1], 256, 8,
            nullptr, nullptr, nullptr, 0, 0);

  // ---- level 2 ----
  pool(XS1, 2048, 64, pw[1], perm2, rank2, XA);
  transpose_k<<<dim3(64, 64), dim3(32, 8), 0, stream>>>(A1, A1T, 2048);
  mfma_ntp_k<<<dim3(8, 8, 4), dim3(256), 0, stream>>>(A1, A1T, perm2, Pbuf, 1024, 2048, 512);
  mfredrow_k<<<dim3(1024), dim3(WG), 0, stream>>>(Pbuf, A2, 1024, 4, dinvL[2], fixvL[2]);
  gcn_dense(A2, 1024, XA, 64, Wd[2], 128, bd[2], 1, XS2, dinvL[2], fixvL[2], 128, 8,
            nullptr, nullptr, nullptr, 0, 0);

  // ---- level 3 ----
  pool(XS2, 1024, 128, pw[2], perm3, rank3, XA);
  augsgemm(A2, perm3, A3, 512, 1024, dinvL[3], fixvL[3]);
  gcn_dense(A3, 512, XA, 128, Wd[3], 256, bd[3], 1, XS3, dinvL[3], fixvL[3], 64, 8,
            nullptr, nullptr, nullptr, 0, 0);

  // ---- level 4 ----
  pool(XS3, 512, 256, pw[3], perm4, rank4, XA);
  augsgemm(A3, perm4, A4, 256, 512, dinvL[4], fixvL[4]);
  gcn_dense(A4, 256, XA, 256, Wd[4], 512, bd[4], 1, XB, dinvL[4], fixvL[4], 64, 4,
            nullptr, nullptr, nullptr, 0, 0);

  // ---- up path (concat fused into the xW GEMM via cat-L mode) ----
  gcn_dense(A3, 512, nullptr, 512, Wu[0], 256, bu[0], 1, XB, dinvL[3], fixvL[3], 64, 8,
            XS3, XB, rank4, 256, 512);
  gcn_dense(A2, 1024, nullptr, 256, Wu[1], 128, bu[1], 1, XB, dinvL[2], fixvL[2], 128, 8,
            XS2, XB, rank3, 128, 256);
  gcn_dense(A1, 2048, nullptr, 128, Wu[2], 64, bu[2], 1, XB, dinvL[1], fixvL[1], 256, 8,
            XS1, XB, rank2, 64, 128);
  sgemm(nullptr, Wu[3], y, 4096, 32, 64, dinvL[0], nullptr, 0, 0, 0,
        XS0, XB, rank1, 32, 64);
  spmv_k<1, 0><<<dim3(1024), dim3(256), 0, stream>>>(offb, bys, y, 32, dinvL[0], fixvL[0], bu[3], 0, XB);

  // ---- final GCN (sparse A0) + fused softmax ----
  sgemm(XB, Wo, y, 4096, 37, 32, dinvL[0], nullptr, 0, 0, 0, nullptr, nullptr, nullptr, 0, 0);
  spmv_k<0, 1><<<dim3(1024), dim3(256), 0, stream>>>(offb, bys, y, 37, dinvL[0], fixvL[0], bo, 0, out);
}